// Round 7
// baseline (5107.590 us; speedup 1.0000x reference)
//
#include <hip/hip_runtime.h>
#include <hip/hip_fp16.h>

#define NPART 131072
#define QDIM 32
#define DDIM 64
#define HDIM 50
#define STEPS 16
#define DT 0.1f
#define LN_EPS 1e-5f
#define INV_H 0.02f   // 1/50
#define ODIM 65       // output row stride

// padded weight strides (floats)
#define S56 56
#define S64 64
#define S32 32
// ws layout (float offsets); all 16B-aligned
#define OFF_W1T 0        // 51 x 64
#define OFF_W2T 3264     // 51 x 56
#define OFF_UT  6120     // 51 x 56
#define OFF_M   8976     // 51 x 56
#define OFF_W3  11832    // 51 x 32
#define OFF_SV  13464    // 50
#define WS_TOT  13514

typedef float f4a __attribute__((ext_vector_type(4)));              // 16B-aligned
typedef float f4u __attribute__((ext_vector_type(4), aligned(4)));  // 4B-aligned

// ---- f16 pair pack/unpack (x2 lo, tw hi) ----
__device__ __forceinline__ float pack2h(float x, float t) {
    const unsigned hx = __half_as_ushort(__float2half_rn(x));
    const unsigned ht = __half_as_ushort(__float2half_rn(t));
    return __uint_as_float((ht << 16) | hx);
}
__device__ __forceinline__ void unpack_lo(float f, float& x) {
    const unsigned u = __float_as_uint(f);
    x = __half2float(__ushort_as_half((unsigned short)(u & 0xffff)));
}
__device__ __forceinline__ void unpack2h(float f, float& x, float& t) {
    const unsigned u = __float_as_uint(f);
    x = __half2float(__ushort_as_half((unsigned short)(u & 0xffff)));
    t = __half2float(__ushort_as_half((unsigned short)(u >> 16)));
}

// ---------------- setup: padded W1T, W2T, UT, M, W3, svec ----------------
__global__ void ode2vae_setup(const float* __restrict__ W1,
                              const float* __restrict__ W2,
                              const float* __restrict__ W3,
                              float* __restrict__ ws)
{
    const int tid = threadIdx.x;
    for (int i = tid; i < WS_TOT; i += 256) ws[i] = 0.f;   // zero pads (row 50 too)
    __syncthreads();
    float* W1T = ws + OFF_W1T;
    float* W2T = ws + OFF_W2T;
    float* UT  = ws + OFF_UT;
    float* M   = ws + OFF_M;
    float* W3p = ws + OFF_W3;
    float* sv  = ws + OFF_SV;
    for (int idx = tid; idx < HDIM * DDIM; idx += 256) {
        const int h = idx / DDIM, d = idx % DDIM;
        W1T[h * S64 + d] = W1[d * HDIM + h];
    }
    for (int idx = tid; idx < HDIM * HDIM; idx += 256) {
        const int j = idx / HDIM, h = idx % HDIM;
        float u = 0.f;
        #pragma unroll
        for (int i = 0; i < QDIM; ++i)
            u = fmaf(W1[i * HDIM + h], W3[j * QDIM + i], u);
        const float w2 = W2[h * HDIM + j];
        float rs = 0.f;
        for (int jj = 0; jj < HDIM; ++jj) rs += W2[h * HDIM + jj];
        W2T[j * S56 + h] = w2;
        UT[j * S56 + h]  = u;
        M[j * S56 + h]   = u * (w2 - INV_H * rs);
    }
    for (int idx = tid; idx < HDIM * QDIM; idx += 256) {
        const int j = idx / QDIM, i = idx % QDIM;
        W3p[j * S32 + i] = W3[j * QDIM + i];
    }
    if (tid < HDIM) {
        float acc = 0.f;
        #pragma unroll
        for (int i = 0; i < QDIM; ++i) {
            float rs1 = 0.f;
            for (int h = 0; h < HDIM; ++h) rs1 += W1[i * HDIM + h];
            acc = fmaf(rs1, W3[tid * QDIM + i], acc);
        }
        sv[tid] = acc;
    }
}

// ---- chunk load / dot / saxpy primitives (all statically indexed) ----
#define LD7(D, SRC) { const f4a* S_ = (const f4a*)(SRC); \
    _Pragma("unroll") for (int c_ = 0; c_ < 7; ++c_) D[c_] = S_[c_]; }
#define LD8(D, SRC) { const f4a* S_ = (const f4a*)(SRC); \
    _Pragma("unroll") for (int c_ = 0; c_ < 8; ++c_) D[c_] = S_[c_]; }

#define DOT28ACC(p0, p1, p2, p3, B, V, O) \
    _Pragma("unroll") for (int c_ = 0; c_ < 7; ++c_) { \
        p0 = fmaf(B[c_][0], (V)[(O) + 4*c_ + 0], p0); \
        p1 = fmaf(B[c_][1], (V)[(O) + 4*c_ + 1], p1); \
        p2 = fmaf(B[c_][2], (V)[(O) + 4*c_ + 2], p2); \
        p3 = fmaf(B[c_][3], (V)[(O) + 4*c_ + 3], p3); }

#define DOT32ACC(p0, p1, p2, p3, B, V) \
    _Pragma("unroll") for (int c_ = 0; c_ < 8; ++c_) { \
        p0 = fmaf(B[c_][0], (V)[4*c_ + 0], p0); \
        p1 = fmaf(B[c_][1], (V)[4*c_ + 1], p1); \
        p2 = fmaf(B[c_][2], (V)[4*c_ + 2], p2); \
        p3 = fmaf(B[c_][3], (V)[4*c_ + 3], p3); }

#define DOT28X2(pa0, pa1, pb0, pb1, B, Va, Vb, O) \
    _Pragma("unroll") for (int c_ = 0; c_ < 7; ++c_) { \
        pa0 = fmaf(B[c_][0], (Va)[(O) + 4*c_ + 0], pa0); \
        pb0 = fmaf(B[c_][0], (Vb)[(O) + 4*c_ + 0], pb0); \
        pa1 = fmaf(B[c_][1], (Va)[(O) + 4*c_ + 1], pa1); \
        pb1 = fmaf(B[c_][1], (Vb)[(O) + 4*c_ + 1], pb1); \
        pa0 = fmaf(B[c_][2], (Va)[(O) + 4*c_ + 2], pa0); \
        pb0 = fmaf(B[c_][2], (Vb)[(O) + 4*c_ + 2], pb0); \
        pa1 = fmaf(B[c_][3], (Va)[(O) + 4*c_ + 3], pa1); \
        pb1 = fmaf(B[c_][3], (Vb)[(O) + 4*c_ + 3], pb1); }

#define SAXPY28(B, sc, D, O) \
    _Pragma("unroll") for (int c_ = 0; c_ < 7; ++c_) { \
        (D)[(O) + 4*c_ + 0] = fmaf(B[c_][0], sc, (D)[(O) + 4*c_ + 0]); \
        (D)[(O) + 4*c_ + 1] = fmaf(B[c_][1], sc, (D)[(O) + 4*c_ + 1]); \
        (D)[(O) + 4*c_ + 2] = fmaf(B[c_][2], sc, (D)[(O) + 4*c_ + 2]); \
        (D)[(O) + 4*c_ + 3] = fmaf(B[c_][3], sc, (D)[(O) + 4*c_ + 3]); }

#define SAXPY32(B, sc, D) \
    _Pragma("unroll") for (int c_ = 0; c_ < 8; ++c_) { \
        (D)[4*c_ + 0] = fmaf(B[c_][0], sc, (D)[4*c_ + 0]); \
        (D)[4*c_ + 1] = fmaf(B[c_][1], sc, (D)[4*c_ + 1]); \
        (D)[4*c_ + 2] = fmaf(B[c_][2], sc, (D)[4*c_ + 2]); \
        (D)[4*c_ + 3] = fmaf(B[c_][3], sc, (D)[4*c_ + 3]); }

__global__ __launch_bounds__(64, 1)
void ode2vae_main(const float* __restrict__ z0, const float* __restrict__ logp0,
                  const float* __restrict__ b1, const float* __restrict__ g1,
                  const float* __restrict__ be1,
                  const float* __restrict__ b2, const float* __restrict__ g2,
                  const float* __restrict__ be2, const float* __restrict__ b3,
                  const float* __restrict__ wsc,
                  float* out)                 // no __restrict__: we read our own writes
{
    __shared__ float lds[HDIM * 64];         // 50 slots x 64 lanes: a1 -> a2 -> f16(x2,tw)
    const int lane = threadIdx.x;
    const int n = blockIdx.x * 64 + lane;
    float* const L = lds + lane;

    // opaque zero in a VGPR: forces weight-row loads onto the vector pipe
    // (same address across lanes -> 1-line broadcast), enabling VGPR dbuf.
    int tz = 0;
    asm volatile("" : "+v"(tz));
    const float* W1Tp = wsc + OFF_W1T + tz;
    const float* W2Tp = wsc + OFF_W2T + tz;
    const float* UTp  = wsc + OFF_UT  + tz;
    const float* Mp   = wsc + OFF_M   + tz;
    const float* W3p  = wsc + OFF_W3  + tz;
    const float* svec = wsc + OFF_SV;        // stays scalar

    float lp = logp0[n];
    const float* const zrow0 = z0 + (size_t)n * DDIM;

    for (int s = 0; s < STEPS; ++s) {
        float* const odst = out + ((size_t)s * NPART + (size_t)n) * ODIM;
        const float* const zprev = (s == 0) ? zrow0
            : (out + ((size_t)(s - 1) * NPART + (size_t)n) * ODIM);

        // ======== A: z reload, a1 rows (W1Tp, 2x32 chunks) -> LDS ========
        float zq[QDIM], zs[QDIM];
        #pragma unroll
        for (int k = 0; k < 8; ++k) {
            f4u v = *(const f4u*)(zprev + 4 * k);
            zq[4*k] = v[0]; zq[4*k+1] = v[1]; zq[4*k+2] = v[2]; zq[4*k+3] = v[3];
        }
        #pragma unroll
        for (int k = 0; k < 8; ++k) {
            f4u v = *(const f4u*)(zprev + QDIM + 4 * k);
            zs[4*k] = v[0]; zs[4*k+1] = v[1]; zs[4*k+2] = v[2]; zs[4*k+3] = v[3];
        }
        float m1a = 0.f, v1a = 0.f;
        {
            f4a bA[8], bB[8];
            LD8(bA, W1Tp);
            #pragma unroll 1
            for (int h = 0; h < HDIM; ++h) {
                const float* r = W1Tp + h * S64;
                LD8(bB, r + 32);
                float p0 = 0.f, p1 = 0.f, p2 = 0.f, p3 = 0.f;
                DOT32ACC(p0, p1, p2, p3, bA, zq);
                LD8(bA, r + S64);                       // chunk0 of row h+1 (row50 = zeros)
                DOT32ACC(p0, p1, p2, p3, bB, zs);
                const float a1h = ((p0 + p1) + (p2 + p3)) + b1[h];
                L[h * 64] = a1h;
                m1a += a1h;
                v1a = fmaf(a1h, a1h, v1a);
            }
        }
        // zs_new = zs + DT*zq  (old zq); store; both z halves die here
        #pragma unroll
        for (int k = 0; k < QDIM; ++k) zs[k] = fmaf(DT, zq[k], zs[k]);
        #pragma unroll
        for (int k = 0; k < 8; ++k) {
            f4u v = {zs[4*k], zs[4*k+1], zs[4*k+2], zs[4*k+3]};
            *(f4u*)(odst + QDIM + 4 * k) = v;
        }
        const float m1 = m1a * INV_H;
        float var1 = v1a * INV_H - m1 * m1;
        var1 = var1 > 0.f ? var1 : 0.f;
        const float r1 = rsqrtf(var1 + LN_EPS);

        // ======== B: xh1, hh (padded to 56, pads = 0) ========
        float xh1[S56], hh[S56];
        #pragma unroll
        for (int h = 0; h < HDIM; ++h) {
            const float xh = (L[h * 64] - m1) * r1;
            xh1[h] = xh;
            const float y = fmaf(xh, g1[h], be1[h]);
            const float e = __expf(y);
            hh[h] = (y > 0.f) ? y : (e - 1.f);          // celu
        }
        #pragma unroll
        for (int h = HDIM; h < S56; ++h) { xh1[h] = 0.f; hh[h] = 0.f; }

        // ======== C: a2 rows (W2Tp) -> LDS ========
        float m2a = 0.f, v2a = 0.f;
        {
            f4a cA[7], cB[7];
            LD7(cA, W2Tp);
            #pragma unroll 1
            for (int j = 0; j < HDIM; ++j) {
                const float* r = W2Tp + j * S56;
                LD7(cB, r + 28);
                float p0 = 0.f, p1 = 0.f, p2 = 0.f, p3 = 0.f;
                DOT28ACC(p0, p1, p2, p3, cA, hh, 0);
                LD7(cA, r + S56);
                DOT28ACC(p0, p1, p2, p3, cB, hh, 28);
                const float a2j = ((p0 + p1) + (p2 + p3)) + b2[j];
                L[j * 64] = a2j;
                m2a += a2j;
                v2a = fmaf(a2j, a2j, v2a);
            }
        }
        const float m2 = m2a * INV_H;
        float var2 = v2a * INV_H - m2 * m2;
        var2 = var2 > 0.f ? var2 : 0.f;
        const float r2 = rsqrtf(var2 + LN_EPS);

        // ======== D1: x2, t = UT_j . xh1, tw; pack; scalar sums ========
        float suA = 0.f, syA = 0.f, tuA = 0.f, tyA = 0.f;
        {
            f4a cA[7], cB[7];
            LD7(cA, UTp);
            #pragma unroll 1
            for (int j = 0; j < HDIM; ++j) {
                const float* r = UTp + j * S56;
                const float x2 = (L[j * 64] - m2) * r2;
                LD7(cB, r + 28);
                float p0 = 0.f, p1 = 0.f, p2 = 0.f, p3 = 0.f;
                DOT28ACC(p0, p1, p2, p3, cA, xh1, 0);
                LD7(cA, r + S56);
                DOT28ACC(p0, p1, p2, p3, cB, xh1, 28);
                const float t = (p0 + p1) + (p2 + p3);
                const float g2j = g2[j];
                const float y = fmaf(x2, g2j, be2[j]);
                const float e = __expf(y);
                const float w2vj = ((y > 0.f) ? 1.f : e) * (g2j * r2);
                const float tw = w2vj * t;
                L[j * 64] = pack2h(x2, tw);
                tuA += tw; tyA = fmaf(tw, x2, tyA);
                const float sw = svec[j] * w2vj;
                suA += sw; syA = fmaf(sw, x2, syA);
            }
        }
        const float suH = suA * INV_H, syH = syA * INV_H;
        const float tuH = tuA * INV_H, tyH = tyA * INV_H;

        // ======== G: w1v; xh1 -> w1x in place (hh dead) ========
        float w1v[S56];
        #pragma unroll
        for (int h = 0; h < HDIM; ++h) {
            const float gg = g1[h];
            const float y = fmaf(xh1[h], gg, be1[h]);
            const float e = __expf(y);
            const float w = ((y > 0.f) ? 1.f : e) * (gg * r1);
            w1v[h] = w;
            xh1[h] *= w;                                 // w1x
        }
        #pragma unroll
        for (int h = HDIM; h < S56; ++h) w1v[h] = 0.f;

        // ======== F1: S2 (w1v), S3 (w1x) over W2Tp rows ========
        float S2 = 0.f, S3 = 0.f;
        {
            f4a cA[7], cB[7];
            LD7(cA, W2Tp);
            #pragma unroll 1
            for (int j = 0; j < HDIM; ++j) {
                const float* r = W2Tp + j * S56;
                float x2, tw; unpack2h(L[j * 64], x2, tw);
                LD7(cB, r + 28);
                float a0 = 0.f, a1_ = 0.f, bb0 = 0.f, bb1 = 0.f;
                DOT28X2(a0, a1_, bb0, bb1, cA, w1v, xh1, 0);
                LD7(cA, r + S56);
                DOT28X2(a0, a1_, bb0, bb1, cB, w1v, xh1, 28);
                const float g2j = g2[j];
                const float y = fmaf(x2, g2j, be2[j]);
                const float e = __expf(y);
                const float w2vj = ((y > 0.f) ? 1.f : e) * (g2j * r2);
                const float q1 = fmaf(-syH, x2, svec[j] * w2vj - suH);
                const float q2 = fmaf(-tyH, x2, tw - tuH);
                S2 = fmaf(q1, a0 + a1_, S2);
                S3 = fmaf(q2, bb0 + bb1, S3);
            }
        }

        // ======== T1A: Mp rows . w1v (w1x dead) ========
        float T1A = 0.f;
        {
            f4a cA[7], cB[7];
            LD7(cA, Mp);
            #pragma unroll 1
            for (int j = 0; j < HDIM; ++j) {
                const float* r = Mp + j * S56;
                float x2; unpack_lo(L[j * 64], x2);
                LD7(cB, r + 28);
                float p0 = 0.f, p1 = 0.f, p2 = 0.f, p3 = 0.f;
                DOT28ACC(p0, p1, p2, p3, cA, w1v, 0);
                LD7(cA, r + S56);
                DOT28ACC(p0, p1, p2, p3, cB, w1v, 28);
                const float g2j = g2[j];
                const float y = fmaf(x2, g2j, be2[j]);
                const float e = __expf(y);
                const float w2vj = ((y > 0.f) ? 1.f : e) * (g2j * r2);
                T1A = fmaf(w2vj, (p0 + p1) + (p2 + p3), T1A);
            }
        }

        // ======== F2: duy += UT_j * y3_j (saxpy) ========
        float duy[S56];
        #pragma unroll
        for (int h = 0; h < S56; ++h) duy[h] = 0.f;
        {
            f4a cA[7], cB[7];
            LD7(cA, UTp);
            #pragma unroll 1
            for (int j = 0; j < HDIM; ++j) {
                const float* r = UTp + j * S56;
                float x2; unpack_lo(L[j * 64], x2);
                const float g2j = g2[j];
                const float y = fmaf(x2, g2j, be2[j]);
                const float e = __expf(y);
                const float w2vj = ((y > 0.f) ? 1.f : e) * (g2j * r2);
                const float y3 = x2 * w2vj;
                LD7(cB, r + 28);
                SAXPY28(cA, y3, duy, 0);
                LD7(cA, r + S56);
                SAXPY28(cB, y3, duy, 28);
            }
        }
        // wduy in place (w1v dies after this)
        #pragma unroll
        for (int h = 0; h < HDIM; ++h) duy[h] *= w1v[h];

        // ======== T1c: W2Tp rows . wduy ========
        float T1c = 0.f;
        {
            f4a cA[7], cB[7];
            LD7(cA, W2Tp);
            #pragma unroll 1
            for (int j = 0; j < HDIM; ++j) {
                const float* r = W2Tp + j * S56;
                float x2; unpack_lo(L[j * 64], x2);
                LD7(cB, r + 28);
                float p0 = 0.f, p1 = 0.f, p2 = 0.f, p3 = 0.f;
                DOT28ACC(p0, p1, p2, p3, cA, duy, 0);
                LD7(cA, r + S56);
                DOT28ACC(p0, p1, p2, p3, cB, duy, 28);
                T1c = fmaf(x2, (p0 + p1) + (p2 + p3), T1c);
            }
        }
        const float tr = T1A - (T1c + S2 + S3) * INV_H;

        // ======== reload old zq early (latency hidden under dv pass) ========
        float zqo[QDIM];
        #pragma unroll
        for (int k = 0; k < 8; ++k) {
            f4u v = *(const f4u*)(zprev + 4 * k);
            zqo[4*k] = v[0]; zqo[4*k+1] = v[1]; zqo[4*k+2] = v[2]; zqo[4*k+3] = v[3];
        }

        // ======== dv = h2 @ W3 + b3 (W3p rows, 32-chunk, A/B by unroll-2) ========
        float dv[QDIM];
        #pragma unroll
        for (int i = 0; i < QDIM; ++i) dv[i] = b3[i];
        {
            f4a dA[8], dB[8];
            LD8(dA, W3p);
            #pragma unroll 1
            for (int j = 0; j < HDIM; j += 2) {
                const float* r = W3p + j * S32;
                float x2a; unpack_lo(L[j * 64], x2a);
                const float ya = fmaf(x2a, g2[j], be2[j]);
                const float ea = __expf(ya);
                const float h2a = (ya > 0.f) ? ya : (ea - 1.f);
                LD8(dB, r + S32);
                SAXPY32(dA, h2a, dv);
                float x2b; unpack_lo(L[(j + 1) * 64], x2b);
                const float yb = fmaf(x2b, g2[j + 1], be2[j + 1]);
                const float eb = __expf(yb);
                const float h2b = (yb > 0.f) ? yb : (eb - 1.f);
                LD8(dA, r + 2 * S32);                    // row j+2 (row50 = zeros)
                SAXPY32(dB, h2b, dv);
            }
        }

        // ======== update zq, lp; store ========
        lp = fmaf(-DT, tr, lp);
        #pragma unroll
        for (int i = 0; i < QDIM; ++i) zqo[i] = fmaf(DT, dv[i], zqo[i]);
        #pragma unroll
        for (int k = 0; k < 8; ++k) {
            f4u v = {zqo[4*k], zqo[4*k+1], zqo[4*k+2], zqo[4*k+3]};
            *(f4u*)(odst + 4 * k) = v;
        }
        odst[DDIM] = lp;
    }
}

extern "C" void kernel_launch(void* const* d_in, const int* in_sizes, int n_in,
                              void* d_out, int out_size, void* d_ws, size_t ws_size,
                              hipStream_t stream)
{
    const float* z0    = (const float*)d_in[0];
    const float* logp0 = (const float*)d_in[1];
    const float* W1    = (const float*)d_in[2];
    const float* b1    = (const float*)d_in[3];
    const float* g1    = (const float*)d_in[4];
    const float* be1   = (const float*)d_in[5];
    const float* W2    = (const float*)d_in[6];
    const float* b2    = (const float*)d_in[7];
    const float* g2    = (const float*)d_in[8];
    const float* be2   = (const float*)d_in[9];
    const float* W3    = (const float*)d_in[10];
    const float* b3    = (const float*)d_in[11];
    float* out = (float*)d_out;
    float* ws  = (float*)d_ws;

    hipLaunchKernelGGL(ode2vae_setup, dim3(1), dim3(256), 0, stream, W1, W2, W3, ws);
    hipLaunchKernelGGL(ode2vae_main, dim3(NPART / 64), dim3(64), 0, stream,
                       z0, logp0, b1, g1, be1, b2, g2, be2, b3, ws, out);
}

// Round 8
// 2896.837 us; speedup vs baseline: 1.7632x; 1.7632x over previous
//
#include <hip/hip_runtime.h>
#include <hip/hip_fp16.h>

#define NPART 131072
#define QDIM 32
#define DDIM 64
#define HDIM 50
#define STEPS 16
#define DT 0.1f
#define LN_EPS 1e-5f
#define INV_H 0.02f   // 1/50
#define ODIM 65       // output row stride

// ---- ws / LDS weight-region layout (float units) ----
#define WS_W1T  0       // f32 [51][64]
#define WS_W3   3264    // f32 [51][32]
#define WS_W2TH 4896    // u32 [51][28]  f16 pairs (h even lo, h odd hi)
#define WS_UTH  6324    // u32 [51][28]
#define WS_MH   7752    // u32 [51][28]
#define WS_JV   9180    // f32 [51][4]  {g2, be2, b2, sv}
#define WS_HV   9384    // f32 [51][4]  {b1, g1, be1, 0}
#define WS_TOT  9588

#define SLOT_FLOATS 25600          // 50 slots x 512 lanes
#define LDS_FLOATS  (SLOT_FLOATS + WS_TOT)   // 35188 floats = 140752 B

typedef float f4a __attribute__((ext_vector_type(4)));              // 16B-aligned
typedef float f4u __attribute__((ext_vector_type(4), aligned(4)));  // 4B-aligned
typedef unsigned int u32;

// ---- f16 pair pack/unpack (x2 lo, tw hi) ----
__device__ __forceinline__ float pack2h(float x, float t) {
    const unsigned hx = __half_as_ushort(__float2half_rn(x));
    const unsigned ht = __half_as_ushort(__float2half_rn(t));
    return __uint_as_float((ht << 16) | hx);
}
__device__ __forceinline__ void unpack_lo(float f, float& x) {
    const unsigned u = __float_as_uint(f);
    x = __half2float(__ushort_as_half((unsigned short)(u & 0xffff)));
}
__device__ __forceinline__ void unpack2h(float f, float& x, float& t) {
    const unsigned u = __float_as_uint(f);
    x = __half2float(__ushort_as_half((unsigned short)(u & 0xffff)));
    t = __half2float(__ushort_as_half((unsigned short)(u >> 16)));
}
__device__ __forceinline__ u32 packh2(float a, float b) {
    return (u32)__half_as_ushort(__float2half_rn(a)) |
           ((u32)__half_as_ushort(__float2half_rn(b)) << 16);
}

// ---------------- setup ----------------
__global__ void ode2vae_setup(const float* __restrict__ W1,
                              const float* __restrict__ W2,
                              const float* __restrict__ W3,
                              const float* __restrict__ b1, const float* __restrict__ g1,
                              const float* __restrict__ be1,
                              const float* __restrict__ b2, const float* __restrict__ g2,
                              const float* __restrict__ be2,
                              float* __restrict__ ws)
{
    const int tid = threadIdx.x;
    for (int i = tid; i < WS_TOT; i += 256) ws[i] = 0.f;
    __syncthreads();
    // W1T f32
    for (int idx = tid; idx < HDIM * DDIM; idx += 256) {
        const int h = idx / DDIM, d = idx % DDIM;
        ws[WS_W1T + h * 64 + d] = W1[d * HDIM + h];
    }
    // W3 f32 (row-padded to 32; QDIM==32 so exact)
    for (int idx = tid; idx < HDIM * QDIM; idx += 256) {
        const int j = idx / QDIM, i = idx % QDIM;
        ws[WS_W3 + j * 32 + i] = W3[j * QDIM + i];
    }
    // f16-pair tables
    u32* W2TH = (u32*)(ws + WS_W2TH);
    u32* UTH  = (u32*)(ws + WS_UTH);
    u32* MH   = (u32*)(ws + WS_MH);
    for (int idx = tid; idx < HDIM * 28; idx += 256) {
        const int j = idx / 28, k = idx % 28;
        float w2p[2], up[2], mp[2];
        #pragma unroll
        for (int s_ = 0; s_ < 2; ++s_) {
            const int h = 2 * k + s_;
            if (h < HDIM) {
                float u = 0.f;
                #pragma unroll
                for (int i = 0; i < QDIM; ++i)
                    u = fmaf(W1[i * HDIM + h], W3[j * QDIM + i], u);
                const float w2 = W2[h * HDIM + j];
                float rs = 0.f;
                for (int jj = 0; jj < HDIM; ++jj) rs += W2[h * HDIM + jj];
                w2p[s_] = w2; up[s_] = u; mp[s_] = u * (w2 - INV_H * rs);
            } else { w2p[s_] = 0.f; up[s_] = 0.f; mp[s_] = 0.f; }
        }
        W2TH[j * 28 + k] = packh2(w2p[0], w2p[1]);
        UTH[j * 28 + k]  = packh2(up[0], up[1]);
        MH[j * 28 + k]   = packh2(mp[0], mp[1]);
    }
    // jvec / hvec
    if (tid < HDIM) {
        float acc = 0.f;
        #pragma unroll
        for (int i = 0; i < QDIM; ++i) {
            float rs1 = 0.f;
            for (int h = 0; h < HDIM; ++h) rs1 += W1[i * HDIM + h];
            acc = fmaf(rs1, W3[tid * QDIM + i], acc);
        }
        ws[WS_JV + tid * 4 + 0] = g2[tid];
        ws[WS_JV + tid * 4 + 1] = be2[tid];
        ws[WS_JV + tid * 4 + 2] = b2[tid];
        ws[WS_JV + tid * 4 + 3] = acc;
        ws[WS_HV + tid * 4 + 0] = b1[tid];
        ws[WS_HV + tid * 4 + 1] = g1[tid];
        ws[WS_HV + tid * 4 + 2] = be1[tid];
        ws[WS_HV + tid * 4 + 3] = 0.f;
    }
}

// ---- f16-pair row dot: res = row . V  (V padded to 56, zeros) ----
#define DOTH(res, rowp, V)                                              \
    {                                                                   \
        float p0 = 0.f, p1 = 0.f, p2 = 0.f, p3 = 0.f;                   \
        const uint4* R_ = (const uint4*)(rowp);                         \
        _Pragma("unroll")                                               \
        for (int c_ = 0; c_ < 7; ++c_) {                                \
            const uint4 u_ = R_[c_];                                    \
            const __half2 ha = *(const __half2*)&u_.x;                  \
            const __half2 hb = *(const __half2*)&u_.y;                  \
            const __half2 hc = *(const __half2*)&u_.z;                  \
            const __half2 hd = *(const __half2*)&u_.w;                  \
            p0 = fmaf(__low2float(ha),  (V)[8*c_ + 0], p0);             \
            p1 = fmaf(__high2float(ha), (V)[8*c_ + 1], p1);             \
            p2 = fmaf(__low2float(hb),  (V)[8*c_ + 2], p2);             \
            p3 = fmaf(__high2float(hb), (V)[8*c_ + 3], p3);             \
            p0 = fmaf(__low2float(hc),  (V)[8*c_ + 4], p0);             \
            p1 = fmaf(__high2float(hc), (V)[8*c_ + 5], p1);             \
            p2 = fmaf(__low2float(hd),  (V)[8*c_ + 6], p2);             \
            p3 = fmaf(__high2float(hd), (V)[8*c_ + 7], p3);             \
        }                                                               \
        res = (p0 + p1) + (p2 + p3);                                    \
    }

// ---- dual dot sharing one row ----
#define DOTH2(resA, resB, rowp, VA, VB)                                 \
    {                                                                   \
        float a0 = 0.f, a1_ = 0.f, b0_ = 0.f, b1_ = 0.f;                \
        const uint4* R_ = (const uint4*)(rowp);                         \
        _Pragma("unroll")                                               \
        for (int c_ = 0; c_ < 7; ++c_) {                                \
            const uint4 u_ = R_[c_];                                    \
            const __half2 ha = *(const __half2*)&u_.x;                  \
            const __half2 hb = *(const __half2*)&u_.y;                  \
            const __half2 hc = *(const __half2*)&u_.z;                  \
            const __half2 hd = *(const __half2*)&u_.w;                  \
            a0  = fmaf(__low2float(ha),  (VA)[8*c_ + 0], a0);           \
            b0_ = fmaf(__low2float(ha),  (VB)[8*c_ + 0], b0_);          \
            a1_ = fmaf(__high2float(ha), (VA)[8*c_ + 1], a1_);          \
            b1_ = fmaf(__high2float(ha), (VB)[8*c_ + 1], b1_);          \
            a0  = fmaf(__low2float(hb),  (VA)[8*c_ + 2], a0);           \
            b0_ = fmaf(__low2float(hb),  (VB)[8*c_ + 2], b0_);          \
            a1_ = fmaf(__high2float(hb), (VA)[8*c_ + 3], a1_);          \
            b1_ = fmaf(__high2float(hb), (VB)[8*c_ + 3], b1_);          \
            a0  = fmaf(__low2float(hc),  (VA)[8*c_ + 4], a0);           \
            b0_ = fmaf(__low2float(hc),  (VB)[8*c_ + 4], b0_);          \
            a1_ = fmaf(__high2float(hc), (VA)[8*c_ + 5], a1_);          \
            b1_ = fmaf(__high2float(hc), (VB)[8*c_ + 5], b1_);          \
            a0  = fmaf(__low2float(hd),  (VA)[8*c_ + 6], a0);           \
            b0_ = fmaf(__low2float(hd),  (VB)[8*c_ + 6], b0_);          \
            a1_ = fmaf(__high2float(hd), (VA)[8*c_ + 7], a1_);          \
            b1_ = fmaf(__high2float(hd), (VB)[8*c_ + 7], b1_);          \
        }                                                               \
        resA = a0 + a1_; resB = b0_ + b1_;                              \
    }

// ---- f16-pair row saxpy: D += row * sc ----
#define SAXPYH(rowp, sc, D)                                             \
    {                                                                   \
        const uint4* R_ = (const uint4*)(rowp);                         \
        _Pragma("unroll")                                               \
        for (int c_ = 0; c_ < 7; ++c_) {                                \
            const uint4 u_ = R_[c_];                                    \
            const __half2 ha = *(const __half2*)&u_.x;                  \
            const __half2 hb = *(const __half2*)&u_.y;                  \
            const __half2 hc = *(const __half2*)&u_.z;                  \
            const __half2 hd = *(const __half2*)&u_.w;                  \
            (D)[8*c_ + 0] = fmaf(__low2float(ha),  sc, (D)[8*c_ + 0]);  \
            (D)[8*c_ + 1] = fmaf(__high2float(ha), sc, (D)[8*c_ + 1]);  \
            (D)[8*c_ + 2] = fmaf(__low2float(hb),  sc, (D)[8*c_ + 2]);  \
            (D)[8*c_ + 3] = fmaf(__high2float(hb), sc, (D)[8*c_ + 3]);  \
            (D)[8*c_ + 4] = fmaf(__low2float(hc),  sc, (D)[8*c_ + 4]);  \
            (D)[8*c_ + 5] = fmaf(__high2float(hc), sc, (D)[8*c_ + 5]);  \
            (D)[8*c_ + 6] = fmaf(__low2float(hd),  sc, (D)[8*c_ + 6]);  \
            (D)[8*c_ + 7] = fmaf(__high2float(hd), sc, (D)[8*c_ + 7]);  \
        }                                                               \
    }

__global__ __launch_bounds__(512, 2)
void ode2vae_main(const float* __restrict__ z0, const float* __restrict__ logp0,
                  const float* __restrict__ b3,
                  const float* __restrict__ wsc,
                  float* out)                 // no __restrict__: we read our own writes
{
    __shared__ float lds[LDS_FLOATS];
    const int tid = threadIdx.x;
    const int n = blockIdx.x * 512 + tid;

    // cooperative weight-table load, then one barrier; everything after is
    // per-lane private (slots) or read-only broadcast (weights) -> no barriers.
    for (int i = tid; i < WS_TOT; i += 512) lds[SLOT_FLOATS + i] = wsc[i];
    __syncthreads();

    float* const L = lds + tid;                 // slot k at L[k*512]
    const float* LW1T = lds + SLOT_FLOATS + WS_W1T;
    const float* LW3  = lds + SLOT_FLOATS + WS_W3;
    const u32*  LW2TH = (const u32*)(lds + SLOT_FLOATS + WS_W2TH);
    const u32*  LUTH  = (const u32*)(lds + SLOT_FLOATS + WS_UTH);
    const u32*  LMH   = (const u32*)(lds + SLOT_FLOATS + WS_MH);
    const f4a*  LJV   = (const f4a*)(lds + SLOT_FLOATS + WS_JV);
    const f4a*  LHV   = (const f4a*)(lds + SLOT_FLOATS + WS_HV);

    // zq + lp persist in registers; zs round-trips through `out`.
    float zq[QDIM];
    {
        const f4a* zp = (const f4a*)(z0 + (size_t)n * DDIM);
        #pragma unroll
        for (int k = 0; k < 8; ++k) {
            f4a v = zp[k];
            zq[4*k] = v[0]; zq[4*k+1] = v[1]; zq[4*k+2] = v[2]; zq[4*k+3] = v[3];
        }
    }
    float lp = logp0[n];

    for (int s = 0; s < STEPS; ++s) {
        float* const odst = out + ((size_t)s * NPART + (size_t)n) * ODIM;
        const float* const zsprev = (s == 0)
            ? (z0 + (size_t)n * DDIM + QDIM)
            : (out + ((size_t)(s - 1) * NPART + (size_t)n) * ODIM + QDIM);

        // ======== A: load zs; a1 rows (f32, LDS) -> slots ========
        float zs[QDIM];
        #pragma unroll
        for (int k = 0; k < 8; ++k) {
            f4u v = *(const f4u*)(zsprev + 4 * k);
            zs[4*k] = v[0]; zs[4*k+1] = v[1]; zs[4*k+2] = v[2]; zs[4*k+3] = v[3];
        }
        float m1a = 0.f, v1a = 0.f;
        #pragma unroll 1
        for (int h = 0; h < HDIM; ++h) {
            const f4a* r = (const f4a*)(LW1T + h * 64);
            float p0 = 0.f, p1 = 0.f, p2 = 0.f, p3 = 0.f;
            #pragma unroll
            for (int c_ = 0; c_ < 8; ++c_) {
                const f4a v = r[c_];
                p0 = fmaf(v[0], zq[4*c_ + 0], p0);
                p1 = fmaf(v[1], zq[4*c_ + 1], p1);
                p2 = fmaf(v[2], zq[4*c_ + 2], p2);
                p3 = fmaf(v[3], zq[4*c_ + 3], p3);
            }
            #pragma unroll
            for (int c_ = 0; c_ < 8; ++c_) {
                const f4a v = r[8 + c_];
                p0 = fmaf(v[0], zs[4*c_ + 0], p0);
                p1 = fmaf(v[1], zs[4*c_ + 1], p1);
                p2 = fmaf(v[2], zs[4*c_ + 2], p2);
                p3 = fmaf(v[3], zs[4*c_ + 3], p3);
            }
            const f4a hv = LHV[h];
            const float a1h = ((p0 + p1) + (p2 + p3)) + hv[0];
            L[h * 512] = a1h;
            m1a += a1h;
            v1a = fmaf(a1h, a1h, v1a);
        }
        // zs_new = zs + DT*zq (old zq); store; zs dies
        #pragma unroll
        for (int k = 0; k < QDIM; ++k) zs[k] = fmaf(DT, zq[k], zs[k]);
        #pragma unroll
        for (int k = 0; k < 8; ++k) {
            f4u v = {zs[4*k], zs[4*k+1], zs[4*k+2], zs[4*k+3]};
            *(f4u*)(odst + QDIM + 4 * k) = v;
        }
        const float m1 = m1a * INV_H;
        float var1 = v1a * INV_H - m1 * m1;
        var1 = var1 > 0.f ? var1 : 0.f;
        const float r1 = rsqrtf(var1 + LN_EPS);

        // ======== B: xh1, hh ========
        float xh1[56], hh[56];
        #pragma unroll
        for (int h = 0; h < HDIM; ++h) {
            const f4a hv = LHV[h];
            const float xh = (L[h * 512] - m1) * r1;
            xh1[h] = xh;
            const float y = fmaf(xh, hv[1], hv[2]);
            const float e = __expf(y);
            hh[h] = (y > 0.f) ? y : (e - 1.f);          // celu
        }
        #pragma unroll
        for (int h = HDIM; h < 56; ++h) { xh1[h] = 0.f; hh[h] = 0.f; }

        // ======== C: a2 -> slots ========
        float m2a = 0.f, v2a = 0.f;
        #pragma unroll 1
        for (int j = 0; j < HDIM; ++j) {
            float a2j;
            DOTH(a2j, LW2TH + j * 28, hh);
            const f4a jv = LJV[j];
            a2j += jv[2];
            L[j * 512] = a2j;
            m2a += a2j;
            v2a = fmaf(a2j, a2j, v2a);
        }
        const float m2 = m2a * INV_H;
        float var2 = v2a * INV_H - m2 * m2;
        var2 = var2 > 0.f ? var2 : 0.f;
        const float r2 = rsqrtf(var2 + LN_EPS);

        // ======== D1: x2, t, tw; pack; scalar sums ========
        float suA = 0.f, syA = 0.f, tuA = 0.f, tyA = 0.f;
        #pragma unroll 1
        for (int j = 0; j < HDIM; ++j) {
            const float x2 = (L[j * 512] - m2) * r2;
            float t;
            DOTH(t, LUTH + j * 28, xh1);
            const f4a jv = LJV[j];
            const float y = fmaf(x2, jv[0], jv[1]);
            const float e = __expf(y);
            const float w2vj = ((y > 0.f) ? 1.f : e) * (jv[0] * r2);
            const float tw = w2vj * t;
            L[j * 512] = pack2h(x2, tw);
            tuA += tw; tyA = fmaf(tw, x2, tyA);
            const float sw = jv[3] * w2vj;
            suA += sw; syA = fmaf(sw, x2, syA);
        }
        const float suH = suA * INV_H, syH = syA * INV_H;
        const float tuH = tuA * INV_H, tyH = tyA * INV_H;

        // ======== G: w1v; xh1 -> w1x in place (hh dead) ========
        float w1v[56];
        #pragma unroll
        for (int h = 0; h < HDIM; ++h) {
            const f4a hv = LHV[h];
            const float y = fmaf(xh1[h], hv[1], hv[2]);
            const float e = __expf(y);
            const float w = ((y > 0.f) ? 1.f : e) * (hv[1] * r1);
            w1v[h] = w;
            xh1[h] *= w;                                 // w1x
        }
        #pragma unroll
        for (int h = HDIM; h < 56; ++h) w1v[h] = 0.f;

        // ======== F1: S2 (w1v), S3 (w1x) ========
        float S2 = 0.f, S3 = 0.f;
        #pragma unroll 1
        for (int j = 0; j < HDIM; ++j) {
            float x2, tw; unpack2h(L[j * 512], x2, tw);
            float cA_, cB_;
            DOTH2(cA_, cB_, LW2TH + j * 28, w1v, xh1);
            const f4a jv = LJV[j];
            const float y = fmaf(x2, jv[0], jv[1]);
            const float e = __expf(y);
            const float w2vj = ((y > 0.f) ? 1.f : e) * (jv[0] * r2);
            const float q1 = fmaf(-syH, x2, jv[3] * w2vj - suH);
            const float q2 = fmaf(-tyH, x2, tw - tuH);
            S2 = fmaf(q1, cA_, S2);
            S3 = fmaf(q2, cB_, S3);
        }

        // ======== T1A: M rows . w1v ========
        float T1A = 0.f;
        #pragma unroll 1
        for (int j = 0; j < HDIM; ++j) {
            float x2; unpack_lo(L[j * 512], x2);
            float cv;
            DOTH(cv, LMH + j * 28, w1v);
            const f4a jv = LJV[j];
            const float y = fmaf(x2, jv[0], jv[1]);
            const float e = __expf(y);
            const float w2vj = ((y > 0.f) ? 1.f : e) * (jv[0] * r2);
            T1A = fmaf(w2vj, cv, T1A);
        }

        // ======== F2: duy += UT_j * y3_j ========
        float duy[56];
        #pragma unroll
        for (int h = 0; h < 56; ++h) duy[h] = 0.f;
        #pragma unroll 1
        for (int j = 0; j < HDIM; ++j) {
            float x2; unpack_lo(L[j * 512], x2);
            const f4a jv = LJV[j];
            const float y = fmaf(x2, jv[0], jv[1]);
            const float e = __expf(y);
            const float w2vj = ((y > 0.f) ? 1.f : e) * (jv[0] * r2);
            const float y3 = x2 * w2vj;
            SAXPYH(LUTH + j * 28, y3, duy);
        }
        #pragma unroll
        for (int h = 0; h < HDIM; ++h) duy[h] *= w1v[h];   // wduy

        // ======== T1c: W2T rows . wduy ========
        float T1c = 0.f;
        #pragma unroll 1
        for (int j = 0; j < HDIM; ++j) {
            float x2; unpack_lo(L[j * 512], x2);
            float cT;
            DOTH(cT, LW2TH + j * 28, duy);
            T1c = fmaf(x2, cT, T1c);
        }
        const float tr = T1A - (T1c + S2 + S3) * INV_H;

        // ======== dv = h2 @ W3 + b3 (f32 rows, LDS) ========
        float dv[QDIM];
        #pragma unroll
        for (int i = 0; i < QDIM; ++i) dv[i] = b3[i];
        #pragma unroll 1
        for (int j = 0; j < HDIM; ++j) {
            float x2; unpack_lo(L[j * 512], x2);
            const f4a jv = LJV[j];
            const float y = fmaf(x2, jv[0], jv[1]);
            const float e = __expf(y);
            const float h2 = (y > 0.f) ? y : (e - 1.f);
            const f4a* r = (const f4a*)(LW3 + j * 32);
            #pragma unroll
            for (int c_ = 0; c_ < 8; ++c_) {
                const f4a v = r[c_];
                dv[4*c_ + 0] = fmaf(v[0], h2, dv[4*c_ + 0]);
                dv[4*c_ + 1] = fmaf(v[1], h2, dv[4*c_ + 1]);
                dv[4*c_ + 2] = fmaf(v[2], h2, dv[4*c_ + 2]);
                dv[4*c_ + 3] = fmaf(v[3], h2, dv[4*c_ + 3]);
            }
        }

        // ======== update zq, lp; store ========
        lp = fmaf(-DT, tr, lp);
        #pragma unroll
        for (int i = 0; i < QDIM; ++i) zq[i] = fmaf(DT, dv[i], zq[i]);
        #pragma unroll
        for (int k = 0; k < 8; ++k) {
            f4u v = {zq[4*k], zq[4*k+1], zq[4*k+2], zq[4*k+3]};
            *(f4u*)(odst + 4 * k) = v;
        }
        odst[DDIM] = lp;
    }
}

extern "C" void kernel_launch(void* const* d_in, const int* in_sizes, int n_in,
                              void* d_out, int out_size, void* d_ws, size_t ws_size,
                              hipStream_t stream)
{
    const float* z0    = (const float*)d_in[0];
    const float* logp0 = (const float*)d_in[1];
    const float* W1    = (const float*)d_in[2];
    const float* b1    = (const float*)d_in[3];
    const float* g1    = (const float*)d_in[4];
    const float* be1   = (const float*)d_in[5];
    const float* W2    = (const float*)d_in[6];
    const float* b2    = (const float*)d_in[7];
    const float* g2    = (const float*)d_in[8];
    const float* be2   = (const float*)d_in[9];
    const float* W3    = (const float*)d_in[10];
    const float* b3    = (const float*)d_in[11];
    float* out = (float*)d_out;
    float* ws  = (float*)d_ws;

    hipLaunchKernelGGL(ode2vae_setup, dim3(1), dim3(256), 0, stream,
                       W1, W2, W3, b1, g1, be1, b2, g2, be2, ws);
    hipLaunchKernelGGL(ode2vae_main, dim3(NPART / 512), dim3(512), 0, stream,
                       z0, logp0, b3, ws, out);
}

// Round 9
// 1578.136 us; speedup vs baseline: 3.2365x; 1.8356x over previous
//
#include <hip/hip_runtime.h>
#include <hip/hip_fp16.h>

#define NPART 131072
#define QDIM 32
#define DDIM 64
#define HDIM 50
#define STEPS 16
#define DT 0.1f
#define LN_EPS 1e-5f
#define INV_H 0.02f   // 1/50
#define ODIM 65       // output row stride

// ---- ws / LDS weight tables (u32 units; f16 pairs over the contracted dim) ----
#define WS_W1TH 0      // [50][32]  pairs over d (64)
#define WS_W2TH 1600   // [50][28]  pairs over h (50, pad 56)
#define WS_UTH  3000   // [50][28]
#define WS_MH   4400   // [50][28]
#define WS_W3H  5800   // [50][16]  pairs over i (32)
#define WS_JV   6600   // f32 [50][4] {g2, be2, b2, sv}
#define WS_HV   6800   // f32 [50][4] {b1, g1, be1, 0}
#define WS_TOT  7000   // 28000 B

#define SLOT_FLOATS (HDIM * 256)              // 12800 floats = 51.2 KB
#define LDS_FLOATS  (SLOT_FLOATS + WS_TOT)    // 19800 floats = 79.2 KB

typedef float f4a __attribute__((ext_vector_type(4)));
typedef float f4u __attribute__((ext_vector_type(4), aligned(4)));
typedef unsigned int u32;
typedef _Float16 h2f __attribute__((ext_vector_type(2)));

__device__ __forceinline__ h2f as_h2(u32 x) { h2f r; __builtin_memcpy(&r, &x, 4); return r; }
__device__ __forceinline__ u32 h2bits(float a, float b) {
    h2f p; p[0] = (_Float16)a; p[1] = (_Float16)b;
    u32 r; __builtin_memcpy(&r, &p, 4); return r;
}
__device__ __forceinline__ h2f mk_h2(float a, float b) {
    h2f p; p[0] = (_Float16)a; p[1] = (_Float16)b; return p;
}

#if __has_builtin(__builtin_amdgcn_fdot2)
#define FDOT2(a, b, c) __builtin_amdgcn_fdot2((a), (b), (c), false)
#else
#define FDOT2(a, b, c) ((float)(a)[0] * (float)(b)[0] + ((float)(a)[1] * (float)(b)[1] + (c)))
#endif

// ---- f16 x2/tw pair in an f32 slot ----
__device__ __forceinline__ float pack2h(float x, float t) {
    u32 r = h2bits(x, t); float f; __builtin_memcpy(&f, &r, 4); return f;
}
__device__ __forceinline__ void unpack_lo(float f, float& x) {
    u32 u; __builtin_memcpy(&u, &f, 4); h2f p = as_h2(u); x = (float)p[0];
}
__device__ __forceinline__ void unpack2h(float f, float& x, float& t) {
    u32 u; __builtin_memcpy(&u, &f, 4); h2f p = as_h2(u); x = (float)p[0]; t = (float)p[1];
}

// ---------------- setup ----------------
__global__ void ode2vae_setup(const float* __restrict__ W1,
                              const float* __restrict__ W2,
                              const float* __restrict__ W3,
                              const float* __restrict__ b1, const float* __restrict__ g1,
                              const float* __restrict__ be1,
                              const float* __restrict__ b2, const float* __restrict__ g2,
                              const float* __restrict__ be2,
                              float* __restrict__ ws)
{
    const int tid = threadIdx.x;
    u32* wsu = (u32*)ws;
    for (int i = tid; i < WS_TOT; i += 256) wsu[i] = 0u;
    __syncthreads();
    // W1TH: pairs over d
    for (int idx = tid; idx < HDIM * 32; idx += 256) {
        const int h = idx / 32, k = idx % 32;
        wsu[WS_W1TH + h * 32 + k] = h2bits(W1[(2 * k) * HDIM + h], W1[(2 * k + 1) * HDIM + h]);
    }
    // W2TH / UTH / MH: pairs over h
    for (int idx = tid; idx < HDIM * 25; idx += 256) {
        const int j = idx / 25, k = idx % 25;
        float w2p[2], up[2], mp[2];
        #pragma unroll
        for (int s_ = 0; s_ < 2; ++s_) {
            const int h = 2 * k + s_;
            float u = 0.f;
            #pragma unroll
            for (int i = 0; i < QDIM; ++i)
                u = fmaf(W1[i * HDIM + h], W3[j * QDIM + i], u);
            const float w2 = W2[h * HDIM + j];
            float rs = 0.f;
            for (int jj = 0; jj < HDIM; ++jj) rs += W2[h * HDIM + jj];
            w2p[s_] = w2; up[s_] = u; mp[s_] = u * (w2 - INV_H * rs);
        }
        wsu[WS_W2TH + j * 28 + k] = h2bits(w2p[0], w2p[1]);
        wsu[WS_UTH  + j * 28 + k] = h2bits(up[0], up[1]);
        wsu[WS_MH   + j * 28 + k] = h2bits(mp[0], mp[1]);
    }
    // W3H: pairs over i
    for (int idx = tid; idx < HDIM * 16; idx += 256) {
        const int j = idx / 16, k = idx % 16;
        wsu[WS_W3H + j * 16 + k] = h2bits(W3[j * QDIM + 2 * k], W3[j * QDIM + 2 * k + 1]);
    }
    if (tid < HDIM) {
        float acc = 0.f;
        #pragma unroll
        for (int i = 0; i < QDIM; ++i) {
            float rs1 = 0.f;
            for (int h = 0; h < HDIM; ++h) rs1 += W1[i * HDIM + h];
            acc = fmaf(rs1, W3[tid * QDIM + i], acc);
        }
        ws[WS_JV + tid * 4 + 0] = g2[tid];
        ws[WS_JV + tid * 4 + 1] = be2[tid];
        ws[WS_JV + tid * 4 + 2] = b2[tid];
        ws[WS_JV + tid * 4 + 3] = acc;
        ws[WS_HV + tid * 4 + 0] = b1[tid];
        ws[WS_HV + tid * 4 + 1] = g1[tid];
        ws[WS_HV + tid * 4 + 2] = be1[tid];
        ws[WS_HV + tid * 4 + 3] = 0.f;
    }
}

// ---- dot over 56 f16 (28 pairs): row = u32* in LDS, P = h2f[28] registers ----
#define DOT56(res, rowp, P)                                           \
    {                                                                 \
        float q0 = 0.f, q1 = 0.f, q2 = 0.f, q3 = 0.f;                 \
        const uint4* R_ = (const uint4*)(rowp);                       \
        _Pragma("unroll")                                             \
        for (int c_ = 0; c_ < 7; ++c_) {                              \
            const uint4 u_ = R_[c_];                                  \
            q0 = FDOT2(as_h2(u_.x), (P)[4*c_ + 0], q0);               \
            q1 = FDOT2(as_h2(u_.y), (P)[4*c_ + 1], q1);               \
            q2 = FDOT2(as_h2(u_.z), (P)[4*c_ + 2], q2);               \
            q3 = FDOT2(as_h2(u_.w), (P)[4*c_ + 3], q3);               \
        }                                                             \
        res = (q0 + q1) + (q2 + q3);                                  \
    }

// ---- dual dot sharing one row ----
#define DOT56X2(resA, resB, rowp, PA, PB)                             \
    {                                                                 \
        float a0 = 0.f, a1_ = 0.f, b0_ = 0.f, b1_ = 0.f;              \
        const uint4* R_ = (const uint4*)(rowp);                       \
        _Pragma("unroll")                                             \
        for (int c_ = 0; c_ < 7; ++c_) {                              \
            const uint4 u_ = R_[c_];                                  \
            a0  = FDOT2(as_h2(u_.x), (PA)[4*c_ + 0], a0);             \
            b0_ = FDOT2(as_h2(u_.x), (PB)[4*c_ + 0], b0_);            \
            a1_ = FDOT2(as_h2(u_.y), (PA)[4*c_ + 1], a1_);            \
            b1_ = FDOT2(as_h2(u_.y), (PB)[4*c_ + 1], b1_);            \
            a0  = FDOT2(as_h2(u_.z), (PA)[4*c_ + 2], a0);             \
            b0_ = FDOT2(as_h2(u_.z), (PB)[4*c_ + 2], b0_);            \
            a1_ = FDOT2(as_h2(u_.w), (PA)[4*c_ + 3], a1_);            \
            b1_ = FDOT2(as_h2(u_.w), (PB)[4*c_ + 3], b1_);            \
        }                                                             \
        resA = a0 + a1_; resB = b0_ + b1_;                            \
    }

// ---- dot over 64 f16 (32 pairs) for phase A ----
#define DOT64(res, rowp, P)                                           \
    {                                                                 \
        float q0 = 0.f, q1 = 0.f, q2 = 0.f, q3 = 0.f;                 \
        const uint4* R_ = (const uint4*)(rowp);                       \
        _Pragma("unroll")                                             \
        for (int c_ = 0; c_ < 8; ++c_) {                              \
            const uint4 u_ = R_[c_];                                  \
            q0 = FDOT2(as_h2(u_.x), (P)[4*c_ + 0], q0);               \
            q1 = FDOT2(as_h2(u_.y), (P)[4*c_ + 1], q1);               \
            q2 = FDOT2(as_h2(u_.z), (P)[4*c_ + 2], q2);               \
            q3 = FDOT2(as_h2(u_.w), (P)[4*c_ + 3], q3);               \
        }                                                             \
        res = (q0 + q1) + (q2 + q3);                                  \
    }

// ---- packed f16 saxpy: D[28] += row * s (v_pk_fma_f16) ----
#define SAXPY56H(rowp, sh, D)                                         \
    {                                                                 \
        const uint4* R_ = (const uint4*)(rowp);                       \
        _Pragma("unroll")                                             \
        for (int c_ = 0; c_ < 7; ++c_) {                              \
            const uint4 u_ = R_[c_];                                  \
            (D)[4*c_ + 0] = as_h2(u_.x) * (sh) + (D)[4*c_ + 0];       \
            (D)[4*c_ + 1] = as_h2(u_.y) * (sh) + (D)[4*c_ + 1];       \
            (D)[4*c_ + 2] = as_h2(u_.z) * (sh) + (D)[4*c_ + 2];       \
            (D)[4*c_ + 3] = as_h2(u_.w) * (sh) + (D)[4*c_ + 3];       \
        }                                                             \
    }
#define SAXPY32H(rowp, sh, D)                                         \
    {                                                                 \
        const uint4* R_ = (const uint4*)(rowp);                       \
        _Pragma("unroll")                                             \
        for (int c_ = 0; c_ < 4; ++c_) {                              \
            const uint4 u_ = R_[c_];                                  \
            (D)[4*c_ + 0] = as_h2(u_.x) * (sh) + (D)[4*c_ + 0];       \
            (D)[4*c_ + 1] = as_h2(u_.y) * (sh) + (D)[4*c_ + 1];       \
            (D)[4*c_ + 2] = as_h2(u_.z) * (sh) + (D)[4*c_ + 2];       \
            (D)[4*c_ + 3] = as_h2(u_.w) * (sh) + (D)[4*c_ + 3];       \
        }                                                             \
    }

__global__ __launch_bounds__(256, 2)
void ode2vae_main(const float* __restrict__ z0, const float* __restrict__ logp0,
                  const float* __restrict__ b3,
                  const float* __restrict__ wsc,
                  float* out)                 // no __restrict__: we read our own writes
{
    __shared__ float lds[LDS_FLOATS];
    const int tid = threadIdx.x;
    const int n = blockIdx.x * 256 + tid;

    for (int i = tid; i < WS_TOT; i += 256)
        ((u32*)lds)[SLOT_FLOATS + i] = ((const u32*)wsc)[i];
    __syncthreads();

    float* const L = lds + tid;                         // slot k at L[k*256]
    const u32* LW1TH = (const u32*)(lds + SLOT_FLOATS) + WS_W1TH;
    const u32* LW2TH = (const u32*)(lds + SLOT_FLOATS) + WS_W2TH;
    const u32* LUTH  = (const u32*)(lds + SLOT_FLOATS) + WS_UTH;
    const u32* LMH   = (const u32*)(lds + SLOT_FLOATS) + WS_MH;
    const u32* LW3H  = (const u32*)(lds + SLOT_FLOATS) + WS_W3H;
    const f4a* LJV   = (const f4a*)(lds + SLOT_FLOATS + WS_JV);
    const f4a* LHV   = (const f4a*)(lds + SLOT_FLOATS + WS_HV);

    float zq[QDIM];
    {
        const f4a* zp = (const f4a*)(z0 + (size_t)n * DDIM);
        #pragma unroll
        for (int k = 0; k < 8; ++k) {
            f4a v = zp[k];
            zq[4*k] = v[0]; zq[4*k+1] = v[1]; zq[4*k+2] = v[2]; zq[4*k+3] = v[3];
        }
    }
    float lp = logp0[n];

    for (int s = 0; s < STEPS; ++s) {
        float* const odst = out + ((size_t)s * NPART + (size_t)n) * ODIM;
        const float* const zsprev = (s == 0)
            ? (z0 + (size_t)n * DDIM + QDIM)
            : (out + ((size_t)(s - 1) * NPART + (size_t)n) * ODIM + QDIM);

        // ======== A: load zs; pack z; a1 rows -> slots (f32) ========
        float zs[QDIM];
        #pragma unroll
        for (int k = 0; k < 8; ++k) {
            f4u v = *(const f4u*)(zsprev + 4 * k);
            zs[4*k] = v[0]; zs[4*k+1] = v[1]; zs[4*k+2] = v[2]; zs[4*k+3] = v[3];
        }
        h2f zp[32];
        #pragma unroll
        for (int k = 0; k < 16; ++k) zp[k] = mk_h2(zq[2*k], zq[2*k+1]);
        #pragma unroll
        for (int k = 0; k < 16; ++k) zp[16 + k] = mk_h2(zs[2*k], zs[2*k+1]);

        float m1a = 0.f, v1a = 0.f;
        #pragma unroll 1
        for (int h = 0; h < HDIM; ++h) {
            float a1h;
            DOT64(a1h, LW1TH + h * 32, zp);
            const f4a hv = LHV[h];
            a1h += hv[0];
            L[h * 256] = a1h;
            m1a += a1h;
            v1a = fmaf(a1h, a1h, v1a);
        }
        // zs_new = zs + DT*zq (old zq); store; zs dies
        #pragma unroll
        for (int k = 0; k < QDIM; ++k) zs[k] = fmaf(DT, zq[k], zs[k]);
        #pragma unroll
        for (int k = 0; k < 8; ++k) {
            f4u v = {zs[4*k], zs[4*k+1], zs[4*k+2], zs[4*k+3]};
            *(f4u*)(odst + QDIM + 4 * k) = v;
        }
        const float m1 = m1a * INV_H;
        float var1 = v1a * INV_H - m1 * m1;
        var1 = var1 > 0.f ? var1 : 0.f;
        const float r1 = rsqrtf(var1 + LN_EPS);

        // ======== B: xh1p, hhp (packed f16 pairs) ========
        h2f xh1p[28], hhp[28];
        #pragma unroll
        for (int hp = 0; hp < 25; ++hp) {
            const float xa = (L[(2*hp) * 256] - m1) * r1;
            const float xb = (L[(2*hp + 1) * 256] - m1) * r1;
            const f4a hva = LHV[2*hp], hvb = LHV[2*hp + 1];
            const float ya = fmaf(xa, hva[1], hva[2]);
            const float yb = fmaf(xb, hvb[1], hvb[2]);
            const float ea = __expf(ya), eb = __expf(yb);
            const float ca = (ya > 0.f) ? ya : (ea - 1.f);
            const float cb = (yb > 0.f) ? yb : (eb - 1.f);
            xh1p[hp] = mk_h2(xa, xb);
            hhp[hp]  = mk_h2(ca, cb);
        }
        #pragma unroll
        for (int hp = 25; hp < 28; ++hp) { xh1p[hp] = mk_h2(0.f, 0.f); hhp[hp] = mk_h2(0.f, 0.f); }

        // ======== C: a2 -> slots (f32) ========
        float m2a = 0.f, v2a = 0.f;
        #pragma unroll 1
        for (int j = 0; j < HDIM; ++j) {
            float a2j;
            DOT56(a2j, LW2TH + j * 28, hhp);
            const f4a jv = LJV[j];
            a2j += jv[2];
            L[j * 256] = a2j;
            m2a += a2j;
            v2a = fmaf(a2j, a2j, v2a);
        }
        const float m2 = m2a * INV_H;
        float var2 = v2a * INV_H - m2 * m2;
        var2 = var2 > 0.f ? var2 : 0.f;
        const float r2 = rsqrtf(var2 + LN_EPS);

        // ======== D1: x2, t, tw; pack (x2,tw) into slot; scalar sums ========
        float suA = 0.f, syA = 0.f, tuA = 0.f, tyA = 0.f;
        #pragma unroll 1
        for (int j = 0; j < HDIM; ++j) {
            const float x2 = (L[j * 256] - m2) * r2;
            float t;
            DOT56(t, LUTH + j * 28, xh1p);
            const f4a jv = LJV[j];
            const float y = fmaf(x2, jv[0], jv[1]);
            const float e = __expf(y);
            const float w2vj = ((y > 0.f) ? 1.f : e) * (jv[0] * r2);
            const float tw = w2vj * t;
            L[j * 256] = pack2h(x2, tw);
            tuA += tw; tyA = fmaf(tw, x2, tyA);
            const float sw = jv[3] * w2vj;
            suA += sw; syA = fmaf(sw, x2, syA);
        }
        const float suH = suA * INV_H, syH = syA * INV_H;
        const float tuH = tuA * INV_H, tyH = tyA * INV_H;

        // ======== G: w1vp, w1xp from xh1p (xh1p dies) ========
        h2f w1vp[28], w1xp[28];
        #pragma unroll
        for (int hp = 0; hp < 25; ++hp) {
            const float xa = (float)xh1p[hp][0], xb = (float)xh1p[hp][1];
            const f4a hva = LHV[2*hp], hvb = LHV[2*hp + 1];
            const float ya = fmaf(xa, hva[1], hva[2]);
            const float yb = fmaf(xb, hvb[1], hvb[2]);
            const float ea = __expf(ya), eb = __expf(yb);
            const float wa = ((ya > 0.f) ? 1.f : ea) * (hva[1] * r1);
            const float wb = ((yb > 0.f) ? 1.f : eb) * (hvb[1] * r1);
            w1vp[hp] = mk_h2(wa, wb);
            w1xp[hp] = mk_h2(wa * xa, wb * xb);
        }
        #pragma unroll
        for (int hp = 25; hp < 28; ++hp) { w1vp[hp] = mk_h2(0.f, 0.f); w1xp[hp] = mk_h2(0.f, 0.f); }

        // ======== F1: S2 (w1v), S3 (w1x) ========
        float S2 = 0.f, S3 = 0.f;
        #pragma unroll 1
        for (int j = 0; j < HDIM; ++j) {
            float x2, tw; unpack2h(L[j * 256], x2, tw);
            float cA_, cB_;
            DOT56X2(cA_, cB_, LW2TH + j * 28, w1vp, w1xp);
            const f4a jv = LJV[j];
            const float y = fmaf(x2, jv[0], jv[1]);
            const float e = __expf(y);
            const float w2vj = ((y > 0.f) ? 1.f : e) * (jv[0] * r2);
            const float q1 = fmaf(-syH, x2, jv[3] * w2vj - suH);
            const float q2 = fmaf(-tyH, x2, tw - tuH);
            S2 = fmaf(q1, cA_, S2);
            S3 = fmaf(q2, cB_, S3);
        }

        // ======== T1A: M rows . w1vp ========
        float T1A = 0.f;
        #pragma unroll 1
        for (int j = 0; j < HDIM; ++j) {
            float x2; unpack_lo(L[j * 256], x2);
            float cv;
            DOT56(cv, LMH + j * 28, w1vp);
            const f4a jv = LJV[j];
            const float y = fmaf(x2, jv[0], jv[1]);
            const float e = __expf(y);
            const float w2vj = ((y > 0.f) ? 1.f : e) * (jv[0] * r2);
            T1A = fmaf(w2vj, cv, T1A);
        }

        // ======== F2: duyp += UT_j * y3_j (packed f16) ========
        h2f duyp[28];
        #pragma unroll
        for (int k = 0; k < 28; ++k) duyp[k] = mk_h2(0.f, 0.f);
        #pragma unroll 1
        for (int j = 0; j < HDIM; ++j) {
            float x2; unpack_lo(L[j * 256], x2);
            const f4a jv = LJV[j];
            const float y = fmaf(x2, jv[0], jv[1]);
            const float e = __expf(y);
            const float w2vj = ((y > 0.f) ? 1.f : e) * (jv[0] * r2);
            const float y3 = x2 * w2vj;
            const h2f y3h = mk_h2(y3, y3);
            SAXPY56H(LUTH + j * 28, y3h, duyp);
        }
        // wduy = duyp * w1vp (packed mul; w1vp dies)
        #pragma unroll
        for (int k = 0; k < 28; ++k) duyp[k] = duyp[k] * w1vp[k];

        // ======== T1c: W2T rows . wduy ========
        float T1c = 0.f;
        #pragma unroll 1
        for (int j = 0; j < HDIM; ++j) {
            float x2; unpack_lo(L[j * 256], x2);
            float cT;
            DOT56(cT, LW2TH + j * 28, duyp);
            T1c = fmaf(x2, cT, T1c);
        }
        const float tr = T1A - (T1c + S2 + S3) * INV_H;

        // ======== dv: dvp += W3_j * h2_j (packed f16) ========
        h2f dvp[16];
        #pragma unroll
        for (int k = 0; k < 16; ++k) dvp[k] = mk_h2(0.f, 0.f);
        #pragma unroll 1
        for (int j = 0; j < HDIM; ++j) {
            float x2; unpack_lo(L[j * 256], x2);
            const f4a jv = LJV[j];
            const float y = fmaf(x2, jv[0], jv[1]);
            const float e = __expf(y);
            const float h2v = (y > 0.f) ? y : (e - 1.f);
            const h2f hb = mk_h2(h2v, h2v);
            SAXPY32H(LW3H + j * 16, hb, dvp);
        }

        // ======== update zq, lp; store ========
        lp = fmaf(-DT, tr, lp);
        #pragma unroll
        for (int k = 0; k < 16; ++k) {
            const float da = (float)dvp[k][0] + b3[2*k];
            const float db = (float)dvp[k][1] + b3[2*k + 1];
            zq[2*k]     = fmaf(DT, da, zq[2*k]);
            zq[2*k + 1] = fmaf(DT, db, zq[2*k + 1]);
        }
        #pragma unroll
        for (int k = 0; k < 8; ++k) {
            f4u v = {zq[4*k], zq[4*k+1], zq[4*k+2], zq[4*k+3]};
            *(f4u*)(odst + 4 * k) = v;
        }
        odst[DDIM] = lp;
    }
}

extern "C" void kernel_launch(void* const* d_in, const int* in_sizes, int n_in,
                              void* d_out, int out_size, void* d_ws, size_t ws_size,
                              hipStream_t stream)
{
    const float* z0    = (const float*)d_in[0];
    const float* logp0 = (const float*)d_in[1];
    const float* W1    = (const float*)d_in[2];
    const float* b1    = (const float*)d_in[3];
    const float* g1    = (const float*)d_in[4];
    const float* be1   = (const float*)d_in[5];
    const float* W2    = (const float*)d_in[6];
    const float* b2    = (const float*)d_in[7];
    const float* g2    = (const float*)d_in[8];
    const float* be2   = (const float*)d_in[9];
    const float* W3    = (const float*)d_in[10];
    const float* b3    = (const float*)d_in[11];
    float* out = (float*)d_out;
    float* ws  = (float*)d_ws;

    hipLaunchKernelGGL(ode2vae_setup, dim3(1), dim3(256), 0, stream,
                       W1, W2, W3, b1, g1, be1, b2, g2, be2, ws);
    hipLaunchKernelGGL(ode2vae_main, dim3(NPART / 256), dim3(256), 0, stream,
                       z0, logp0, b3, ws, out);
}

// Round 10
// 1437.877 us; speedup vs baseline: 3.5522x; 1.0975x over previous
//
#include <hip/hip_runtime.h>
#include <hip/hip_fp16.h>

#define NPART 131072
#define QDIM 32
#define DDIM 64
#define HDIM 50
#define STEPS 16
#define DT 0.1f
#define LN_EPS 1e-5f
#define INV_H 0.02f   // 1/50
#define ODIM 65       // output row stride

// ---- ws / LDS weight tables (u32 units; f16 pairs over the contracted dim) ----
#define WS_W1TH 0      // [50][32]  pairs over d (64)
#define WS_W2TH 1600   // [50][28]  pairs over h (50, pad 56)
#define WS_UTH  3000   // [50][28]
#define WS_MH   4400   // [50][28]
#define WS_W3H  5800   // [50][16]  pairs over i (32)
#define WS_JV   6600   // f32 [50][4] {g2, be2, b2, sv}
#define WS_HV   6800   // f32 [50][4] {b1, g1, be1, 0}
#define WS_TOT  7000   // 28000 B

#define SLOT_FLOATS (HDIM * 256)              // 12800 floats = 51.2 KB
#define LDS_FLOATS  (SLOT_FLOATS + WS_TOT)    // 19800 floats = 79.2 KB

typedef float f4a __attribute__((ext_vector_type(4)));
typedef float f4u __attribute__((ext_vector_type(4), aligned(4)));
typedef unsigned int u32;
typedef _Float16 h2f __attribute__((ext_vector_type(2)));

__device__ __forceinline__ h2f as_h2(u32 x) { h2f r; __builtin_memcpy(&r, &x, 4); return r; }
__device__ __forceinline__ u32 h2bits(float a, float b) {
    h2f p; p[0] = (_Float16)a; p[1] = (_Float16)b;
    u32 r; __builtin_memcpy(&r, &p, 4); return r;
}
__device__ __forceinline__ h2f mk_h2(float a, float b) {
    h2f p; p[0] = (_Float16)a; p[1] = (_Float16)b; return p;
}

#if __has_builtin(__builtin_amdgcn_fdot2)
#define FDOT2(a, b, c) __builtin_amdgcn_fdot2((a), (b), (c), false)
#else
#define FDOT2(a, b, c) ((float)(a)[0] * (float)(b)[0] + ((float)(a)[1] * (float)(b)[1] + (c)))
#endif

// ---- f16 x2/tw pair in an f32 slot ----
__device__ __forceinline__ float pack2h(float x, float t) {
    u32 r = h2bits(x, t); float f; __builtin_memcpy(&f, &r, 4); return f;
}
__device__ __forceinline__ void unpack2h(float f, float& x, float& t) {
    u32 u; __builtin_memcpy(&u, &f, 4); h2f p = as_h2(u); x = (float)p[0]; t = (float)p[1];
}

// ---------------- setup (unchanged from R9) ----------------
__global__ void ode2vae_setup(const float* __restrict__ W1,
                              const float* __restrict__ W2,
                              const float* __restrict__ W3,
                              const float* __restrict__ b1, const float* __restrict__ g1,
                              const float* __restrict__ be1,
                              const float* __restrict__ b2, const float* __restrict__ g2,
                              const float* __restrict__ be2,
                              float* __restrict__ ws)
{
    const int tid = threadIdx.x;
    u32* wsu = (u32*)ws;
    for (int i = tid; i < WS_TOT; i += 256) wsu[i] = 0u;
    __syncthreads();
    for (int idx = tid; idx < HDIM * 32; idx += 256) {
        const int h = idx / 32, k = idx % 32;
        wsu[WS_W1TH + h * 32 + k] = h2bits(W1[(2 * k) * HDIM + h], W1[(2 * k + 1) * HDIM + h]);
    }
    for (int idx = tid; idx < HDIM * 25; idx += 256) {
        const int j = idx / 25, k = idx % 25;
        float w2p[2], up[2], mp[2];
        #pragma unroll
        for (int s_ = 0; s_ < 2; ++s_) {
            const int h = 2 * k + s_;
            float u = 0.f;
            #pragma unroll
            for (int i = 0; i < QDIM; ++i)
                u = fmaf(W1[i * HDIM + h], W3[j * QDIM + i], u);
            const float w2 = W2[h * HDIM + j];
            float rs = 0.f;
            for (int jj = 0; jj < HDIM; ++jj) rs += W2[h * HDIM + jj];
            w2p[s_] = w2; up[s_] = u; mp[s_] = u * (w2 - INV_H * rs);
        }
        wsu[WS_W2TH + j * 28 + k] = h2bits(w2p[0], w2p[1]);
        wsu[WS_UTH  + j * 28 + k] = h2bits(up[0], up[1]);
        wsu[WS_MH   + j * 28 + k] = h2bits(mp[0], mp[1]);
    }
    for (int idx = tid; idx < HDIM * 16; idx += 256) {
        const int j = idx / 16, k = idx % 16;
        wsu[WS_W3H + j * 16 + k] = h2bits(W3[j * QDIM + 2 * k], W3[j * QDIM + 2 * k + 1]);
    }
    if (tid < HDIM) {
        float acc = 0.f;
        #pragma unroll
        for (int i = 0; i < QDIM; ++i) {
            float rs1 = 0.f;
            for (int h = 0; h < HDIM; ++h) rs1 += W1[i * HDIM + h];
            acc = fmaf(rs1, W3[tid * QDIM + i], acc);
        }
        ws[WS_JV + tid * 4 + 0] = g2[tid];
        ws[WS_JV + tid * 4 + 1] = be2[tid];
        ws[WS_JV + tid * 4 + 2] = b2[tid];
        ws[WS_JV + tid * 4 + 3] = acc;
        ws[WS_HV + tid * 4 + 0] = b1[tid];
        ws[WS_HV + tid * 4 + 1] = g1[tid];
        ws[WS_HV + tid * 4 + 2] = be1[tid];
        ws[WS_HV + tid * 4 + 3] = 0.f;
    }
}

// ---- forward dots (f32 accumulate via FDOT2 / fma_mix) ----
#define DOT64(res, rowp, P)                                           \
    {                                                                 \
        float q0 = 0.f, q1 = 0.f, q2 = 0.f, q3 = 0.f;                 \
        const uint4* R_ = (const uint4*)(rowp);                       \
        _Pragma("unroll")                                             \
        for (int c_ = 0; c_ < 8; ++c_) {                              \
            const uint4 u_ = R_[c_];                                  \
            q0 = FDOT2(as_h2(u_.x), (P)[4*c_ + 0], q0);               \
            q1 = FDOT2(as_h2(u_.y), (P)[4*c_ + 1], q1);               \
            q2 = FDOT2(as_h2(u_.z), (P)[4*c_ + 2], q2);               \
            q3 = FDOT2(as_h2(u_.w), (P)[4*c_ + 3], q3);               \
        }                                                             \
        res = (q0 + q1) + (q2 + q3);                                  \
    }
#define DOT56(res, rowp, P)                                           \
    {                                                                 \
        float q0 = 0.f, q1 = 0.f, q2 = 0.f, q3 = 0.f;                 \
        const uint4* R_ = (const uint4*)(rowp);                       \
        _Pragma("unroll")                                             \
        for (int c_ = 0; c_ < 7; ++c_) {                              \
            const uint4 u_ = R_[c_];                                  \
            q0 = FDOT2(as_h2(u_.x), (P)[4*c_ + 0], q0);               \
            q1 = FDOT2(as_h2(u_.y), (P)[4*c_ + 1], q1);               \
            q2 = FDOT2(as_h2(u_.z), (P)[4*c_ + 2], q2);               \
            q3 = FDOT2(as_h2(u_.w), (P)[4*c_ + 3], q3);               \
        }                                                             \
        res = (q0 + q1) + (q2 + q3);                                  \
    }

// ---- trace dots: pure packed-f16 (v_pk_fma_f16, 2 MAC/inst guaranteed) ----
// row preloaded in RB[7] (uint4)
#define LDROW7(RB, SRC) { const uint4* S_ = (const uint4*)(SRC);      \
    _Pragma("unroll") for (int c_ = 0; c_ < 7; ++c_) RB[c_] = S_[c_]; }
#define LDROW4(RB, SRC) { const uint4* S_ = (const uint4*)(SRC);      \
    _Pragma("unroll") for (int c_ = 0; c_ < 4; ++c_) RB[c_] = S_[c_]; }

#define PKDOT_RB(res, RB, P)                                          \
    {                                                                 \
        h2f a0 = mk_h2(0.f, 0.f), a1_ = a0;                           \
        _Pragma("unroll")                                             \
        for (int c_ = 0; c_ < 7; ++c_) {                              \
            a0  = as_h2(RB[c_].x) * (P)[4*c_ + 0] + a0;               \
            a1_ = as_h2(RB[c_].y) * (P)[4*c_ + 1] + a1_;              \
            a0  = as_h2(RB[c_].z) * (P)[4*c_ + 2] + a0;               \
            a1_ = as_h2(RB[c_].w) * (P)[4*c_ + 3] + a1_;              \
        }                                                             \
        a0 = a0 + a1_;                                                \
        res = (float)a0[0] + (float)a0[1];                            \
    }

#define PK3DOT_RB(rA, rB, rC, RB, PA, PB, PC)                         \
    {                                                                 \
        h2f aA = mk_h2(0.f, 0.f), aB = aA, aC = aA;                   \
        _Pragma("unroll")                                             \
        for (int c_ = 0; c_ < 7; ++c_) {                              \
            const h2f x_ = as_h2(RB[c_].x), y_ = as_h2(RB[c_].y);     \
            const h2f z_ = as_h2(RB[c_].z), w_ = as_h2(RB[c_].w);     \
            aA = x_ * (PA)[4*c_ + 0] + aA;                            \
            aB = x_ * (PB)[4*c_ + 0] + aB;                            \
            aC = x_ * (PC)[4*c_ + 0] + aC;                            \
            aA = y_ * (PA)[4*c_ + 1] + aA;                            \
            aB = y_ * (PB)[4*c_ + 1] + aB;                            \
            aC = y_ * (PC)[4*c_ + 1] + aC;                            \
            aA = z_ * (PA)[4*c_ + 2] + aA;                            \
            aB = z_ * (PB)[4*c_ + 2] + aB;                            \
            aC = z_ * (PC)[4*c_ + 2] + aC;                            \
            aA = w_ * (PA)[4*c_ + 3] + aA;                            \
            aB = w_ * (PB)[4*c_ + 3] + aB;                            \
            aC = w_ * (PC)[4*c_ + 3] + aC;                            \
        }                                                             \
        rA = (float)aA[0] + (float)aA[1];                             \
        rB = (float)aB[0] + (float)aB[1];                             \
        rC = (float)aC[0] + (float)aC[1];                             \
    }

#define SAXPY_RB7(RB, sh, D)                                          \
    {                                                                 \
        _Pragma("unroll")                                             \
        for (int c_ = 0; c_ < 7; ++c_) {                              \
            (D)[4*c_ + 0] = as_h2(RB[c_].x) * (sh) + (D)[4*c_ + 0];   \
            (D)[4*c_ + 1] = as_h2(RB[c_].y) * (sh) + (D)[4*c_ + 1];   \
            (D)[4*c_ + 2] = as_h2(RB[c_].z) * (sh) + (D)[4*c_ + 2];   \
            (D)[4*c_ + 3] = as_h2(RB[c_].w) * (sh) + (D)[4*c_ + 3];   \
        }                                                             \
    }
#define SAXPY_RB4(RB, sh, D)                                          \
    {                                                                 \
        _Pragma("unroll")                                             \
        for (int c_ = 0; c_ < 4; ++c_) {                              \
            (D)[4*c_ + 0] = as_h2(RB[c_].x) * (sh) + (D)[4*c_ + 0];   \
            (D)[4*c_ + 1] = as_h2(RB[c_].y) * (sh) + (D)[4*c_ + 1];   \
            (D)[4*c_ + 2] = as_h2(RB[c_].z) * (sh) + (D)[4*c_ + 2];   \
            (D)[4*c_ + 3] = as_h2(RB[c_].w) * (sh) + (D)[4*c_ + 3];   \
        }                                                             \
    }

__global__ __launch_bounds__(256, 2)
void ode2vae_main(const float* __restrict__ z0, const float* __restrict__ logp0,
                  const float* __restrict__ b3,
                  const float* __restrict__ wsc,
                  float* out)                 // no __restrict__: we read our own writes
{
    __shared__ float lds[LDS_FLOATS];
    const int tid = threadIdx.x;
    const int n = blockIdx.x * 256 + tid;

    for (int i = tid; i < WS_TOT; i += 256)
        ((u32*)lds)[SLOT_FLOATS + i] = ((const u32*)wsc)[i];
    __syncthreads();

    float* const L = lds + tid;                         // slot k at L[k*256]
    const u32* LW1TH = (const u32*)(lds + SLOT_FLOATS) + WS_W1TH;
    const u32* LW2TH = (const u32*)(lds + SLOT_FLOATS) + WS_W2TH;
    const u32* LUTH  = (const u32*)(lds + SLOT_FLOATS) + WS_UTH;
    const u32* LMH   = (const u32*)(lds + SLOT_FLOATS) + WS_MH;
    const u32* LW3H  = (const u32*)(lds + SLOT_FLOATS) + WS_W3H;
    const f4a* LJV   = (const f4a*)(lds + SLOT_FLOATS + WS_JV);
    const f4a* LHV   = (const f4a*)(lds + SLOT_FLOATS + WS_HV);

    float zq[QDIM];
    {
        const f4a* zp = (const f4a*)(z0 + (size_t)n * DDIM);
        #pragma unroll
        for (int k = 0; k < 8; ++k) {
            f4a v = zp[k];
            zq[4*k] = v[0]; zq[4*k+1] = v[1]; zq[4*k+2] = v[2]; zq[4*k+3] = v[3];
        }
    }
    float lp = logp0[n];

    for (int s = 0; s < STEPS; ++s) {
        float* const odst = out + ((size_t)s * NPART + (size_t)n) * ODIM;
        const float* const zsprev = (s == 0)
            ? (z0 + (size_t)n * DDIM + QDIM)
            : (out + ((size_t)(s - 1) * NPART + (size_t)n) * ODIM + QDIM);

        // ======== A: load zs; pack z; a1 rows -> slots (f32) ========
        float zs[QDIM];
        #pragma unroll
        for (int k = 0; k < 8; ++k) {
            f4u v = *(const f4u*)(zsprev + 4 * k);
            zs[4*k] = v[0]; zs[4*k+1] = v[1]; zs[4*k+2] = v[2]; zs[4*k+3] = v[3];
        }
        h2f zp[32];
        #pragma unroll
        for (int k = 0; k < 16; ++k) zp[k] = mk_h2(zq[2*k], zq[2*k+1]);
        #pragma unroll
        for (int k = 0; k < 16; ++k) zp[16 + k] = mk_h2(zs[2*k], zs[2*k+1]);

        float m1a = 0.f, v1a = 0.f;
        #pragma unroll 1
        for (int h = 0; h < HDIM; ++h) {
            float a1h;
            DOT64(a1h, LW1TH + h * 32, zp);
            const f4a hv = LHV[h];
            a1h += hv[0];
            L[h * 256] = a1h;
            m1a += a1h;
            v1a = fmaf(a1h, a1h, v1a);
        }
        #pragma unroll
        for (int k = 0; k < QDIM; ++k) zs[k] = fmaf(DT, zq[k], zs[k]);
        #pragma unroll
        for (int k = 0; k < 8; ++k) {
            f4u v = {zs[4*k], zs[4*k+1], zs[4*k+2], zs[4*k+3]};
            *(f4u*)(odst + QDIM + 4 * k) = v;
        }
        const float m1 = m1a * INV_H;
        float var1 = v1a * INV_H - m1 * m1;
        var1 = var1 > 0.f ? var1 : 0.f;
        const float r1 = rsqrtf(var1 + LN_EPS);

        // ======== B+G: xh1p, hhp, w1vp, w1xp (one exp per half) ========
        h2f xh1p[28], hhp[28], w1vp[28], w1xp[28];
        #pragma unroll
        for (int hp = 0; hp < 25; ++hp) {
            const float xa = (L[(2*hp) * 256] - m1) * r1;
            const float xb = (L[(2*hp + 1) * 256] - m1) * r1;
            const f4a hva = LHV[2*hp], hvb = LHV[2*hp + 1];
            const float ya = fmaf(xa, hva[1], hva[2]);
            const float yb = fmaf(xb, hvb[1], hvb[2]);
            const float ea = __expf(ya), eb = __expf(yb);
            const float ca = (ya > 0.f) ? ya : (ea - 1.f);
            const float cb = (yb > 0.f) ? yb : (eb - 1.f);
            const float wa = ((ya > 0.f) ? 1.f : ea) * (hva[1] * r1);
            const float wb = ((yb > 0.f) ? 1.f : eb) * (hvb[1] * r1);
            xh1p[hp] = mk_h2(xa, xb);
            hhp[hp]  = mk_h2(ca, cb);
            w1vp[hp] = mk_h2(wa, wb);
            w1xp[hp] = mk_h2(wa * xa, wb * xb);
        }
        #pragma unroll
        for (int hp = 25; hp < 28; ++hp) {
            xh1p[hp] = mk_h2(0.f, 0.f); hhp[hp] = mk_h2(0.f, 0.f);
            w1vp[hp] = mk_h2(0.f, 0.f); w1xp[hp] = mk_h2(0.f, 0.f);
        }

        // ======== C: a2 -> slots (f32 acc) ========
        float m2a = 0.f, v2a = 0.f;
        #pragma unroll 1
        for (int j = 0; j < HDIM; ++j) {
            float a2j;
            DOT56(a2j, LW2TH + j * 28, hhp);
            const f4a jv = LJV[j];
            a2j += jv[2];
            L[j * 256] = a2j;
            m2a += a2j;
            v2a = fmaf(a2j, a2j, v2a);
        }
        const float m2 = m2a * INV_H;
        float var2 = v2a * INV_H - m2 * m2;
        var2 = var2 > 0.f ? var2 : 0.f;
        const float r2 = rsqrtf(var2 + LN_EPS);

        // ======== P1 (D1+F2): per j: UT row once -> t-dot + duy saxpy ========
        h2f duyp[28];
        #pragma unroll
        for (int k = 0; k < 28; ++k) duyp[k] = mk_h2(0.f, 0.f);
        float suA = 0.f, syA = 0.f, tuA = 0.f, tyA = 0.f;
        #pragma unroll 1
        for (int j = 0; j < HDIM; ++j) {
            uint4 RB[7];
            LDROW7(RB, LUTH + j * 28);
            const float x2 = (L[j * 256] - m2) * r2;
            const f4a jv = LJV[j];
            const float y = fmaf(x2, jv[0], jv[1]);
            const float e = __expf(y);
            const float w2vj = ((y > 0.f) ? 1.f : e) * (jv[0] * r2);
            float t;
            PKDOT_RB(t, RB, xh1p);
            const float tw = w2vj * t;
            const float y3 = x2 * w2vj;
            const h2f y3h = mk_h2(y3, y3);
            SAXPY_RB7(RB, y3h, duyp);
            L[j * 256] = pack2h(x2, tw);
            tuA += tw; tyA = fmaf(tw, x2, tyA);
            const float sw = jv[3] * w2vj;
            suA += sw; syA = fmaf(sw, x2, syA);
        }
        const float suH = suA * INV_H, syH = syA * INV_H;
        const float tuH = tuA * INV_H, tyH = tyA * INV_H;

        // wduy = duyp * w1vp (xh1p dead; w1vp still needed)
        #pragma unroll
        for (int k = 0; k < 28; ++k) duyp[k] = duyp[k] * w1vp[k];

        // ======== P2 (F1+T1A+T1c+dv): one j-pass ========
        float S2 = 0.f, S3 = 0.f, T1c = 0.f, T1A = 0.f;
        h2f dvp[16];
        #pragma unroll
        for (int k = 0; k < 16; ++k) dvp[k] = mk_h2(0.f, 0.f);
        #pragma unroll 1
        for (int j = 0; j < HDIM; ++j) {
            float x2, tw; unpack2h(L[j * 256], x2, tw);
            const f4a jv = LJV[j];
            const float y = fmaf(x2, jv[0], jv[1]);
            const float e = __expf(y);
            const float w2vj = ((y > 0.f) ? 1.f : e) * (jv[0] * r2);
            const float h2v = (y > 0.f) ? y : (e - 1.f);
            const float q1 = fmaf(-syH, x2, jv[3] * w2vj - suH);
            const float q2 = fmaf(-tyH, x2, tw - tuH);
            uint4 RB[7];
            LDROW7(RB, LW2TH + j * 28);
            float cS2, cS3, cTc;
            PK3DOT_RB(cS2, cS3, cTc, RB, w1vp, w1xp, duyp);
            LDROW7(RB, LMH + j * 28);
            float cTA;
            PKDOT_RB(cTA, RB, w1vp);
            uint4 RB4[4];
            LDROW4(RB4, LW3H + j * 16);
            const h2f hb = mk_h2(h2v, h2v);
            SAXPY_RB4(RB4, hb, dvp);
            S2  = fmaf(q1, cS2, S2);
            S3  = fmaf(q2, cS3, S3);
            T1c = fmaf(x2, cTc, T1c);
            T1A = fmaf(w2vj, cTA, T1A);
        }
        const float tr = T1A - (T1c + S2 + S3) * INV_H;

        // ======== update zq, lp; store ========
        lp = fmaf(-DT, tr, lp);
        #pragma unroll
        for (int k = 0; k < 16; ++k) {
            const float da = (float)dvp[k][0] + b3[2*k];
            const float db = (float)dvp[k][1] + b3[2*k + 1];
            zq[2*k]     = fmaf(DT, da, zq[2*k]);
            zq[2*k + 1] = fmaf(DT, db, zq[2*k + 1]);
        }
        #pragma unroll
        for (int k = 0; k < 8; ++k) {
            f4u v = {zq[4*k], zq[4*k+1], zq[4*k+2], zq[4*k+3]};
            *(f4u*)(odst + 4 * k) = v;
        }
        odst[DDIM] = lp;
    }
}

extern "C" void kernel_launch(void* const* d_in, const int* in_sizes, int n_in,
                              void* d_out, int out_size, void* d_ws, size_t ws_size,
                              hipStream_t stream)
{
    const float* z0    = (const float*)d_in[0];
    const float* logp0 = (const float*)d_in[1];
    const float* W1    = (const float*)d_in[2];
    const float* b1    = (const float*)d_in[3];
    const float* g1    = (const float*)d_in[4];
    const float* be1   = (const float*)d_in[5];
    const float* W2    = (const float*)d_in[6];
    const float* b2    = (const float*)d_in[7];
    const float* g2    = (const float*)d_in[8];
    const float* be2   = (const float*)d_in[9];
    const float* W3    = (const float*)d_in[10];
    const float* b3    = (const float*)d_in[11];
    float* out = (float*)d_out;
    float* ws  = (float*)d_ws;

    hipLaunchKernelGGL(ode2vae_setup, dim3(1), dim3(256), 0, stream,
                       W1, W2, W3, b1, g1, be1, b2, g2, be2, ws);
    hipLaunchKernelGGL(ode2vae_main, dim3(NPART / 256), dim3(256), 0, stream,
                       z0, logp0, b3, ws, out);
}

// Round 11
// 1376.891 us; speedup vs baseline: 3.7095x; 1.0443x over previous
//
#include <hip/hip_runtime.h>
#include <hip/hip_fp16.h>

#define NPART 131072
#define QDIM 32
#define DDIM 64
#define HDIM 50
#define STEPS 16
#define DT 0.1f
#define LN_EPS 1e-5f
#define INV_H 0.02f   // 1/50
#define ODIM 65       // output row stride

// ---- ws weight tables (u32 units; f16 pairs over the contracted dim) ----
#define WS_W1TH 0      // [50][32]  pairs over d (64)
#define WS_W2TH 1600   // [50][28]  pairs over h (50, pad 56)
#define WS_UTH  3000   // [50][28]
#define WS_MH   4400   // [50][28]
#define WS_W3H  5800   // [50][16]  pairs over i (32)
#define WS_JV   6600   // f32 [50][4] {g2, be2, b2, sv}
#define WS_HV   6800   // f32 [50][4] {b1, g1, be1, 0}
#define WS_TOT  7000   // 28000 B

// LDS-resident tables: W1TH + W2TH + UTH only (4400 u32 = 17.6 KB)
#define LT_W1TH 0
#define LT_W2TH 1600
#define LT_UTH  3000
#define LT_TOT  4400

#define SLOT_FLOATS (HDIM * 256)              // 12800 floats = 51.2 KB
#define LDS_FLOATS  (SLOT_FLOATS + LT_TOT)    // 17200 floats = 68.8 KB

typedef float f4a __attribute__((ext_vector_type(4)));
typedef float f4u __attribute__((ext_vector_type(4), aligned(4)));
typedef unsigned int u32;
typedef _Float16 h2f __attribute__((ext_vector_type(2)));

__device__ __forceinline__ h2f as_h2(u32 x) { h2f r; __builtin_memcpy(&r, &x, 4); return r; }
__device__ __forceinline__ u32 h2bits(float a, float b) {
    h2f p; p[0] = (_Float16)a; p[1] = (_Float16)b;
    u32 r; __builtin_memcpy(&r, &p, 4); return r;
}
__device__ __forceinline__ h2f mk_h2(float a, float b) {
    h2f p; p[0] = (_Float16)a; p[1] = (_Float16)b; return p;
}

#if __has_builtin(__builtin_amdgcn_fdot2)
#define FDOT2(a, b, c) __builtin_amdgcn_fdot2((a), (b), (c), false)
#else
#define FDOT2(a, b, c) ((float)(a)[0] * (float)(b)[0] + ((float)(a)[1] * (float)(b)[1] + (c)))
#endif

// ---- f16 x2/tw pair in an f32 slot ----
__device__ __forceinline__ float pack2h(float x, float t) {
    u32 r = h2bits(x, t); float f; __builtin_memcpy(&f, &r, 4); return f;
}
__device__ __forceinline__ void unpack2h(float f, float& x, float& t) {
    u32 u; __builtin_memcpy(&u, &f, 4); h2f p = as_h2(u); x = (float)p[0]; t = (float)p[1];
}

// ---------------- setup (same table contents as R9/R10) ----------------
__global__ void ode2vae_setup(const float* __restrict__ W1,
                              const float* __restrict__ W2,
                              const float* __restrict__ W3,
                              const float* __restrict__ b1, const float* __restrict__ g1,
                              const float* __restrict__ be1,
                              const float* __restrict__ b2, const float* __restrict__ g2,
                              const float* __restrict__ be2,
                              float* __restrict__ ws)
{
    const int tid = threadIdx.x;
    u32* wsu = (u32*)ws;
    for (int i = tid; i < WS_TOT; i += 256) wsu[i] = 0u;
    __syncthreads();
    for (int idx = tid; idx < HDIM * 32; idx += 256) {
        const int h = idx / 32, k = idx % 32;
        wsu[WS_W1TH + h * 32 + k] = h2bits(W1[(2 * k) * HDIM + h], W1[(2 * k + 1) * HDIM + h]);
    }
    for (int idx = tid; idx < HDIM * 25; idx += 256) {
        const int j = idx / 25, k = idx % 25;
        float w2p[2], up[2], mp[2];
        #pragma unroll
        for (int s_ = 0; s_ < 2; ++s_) {
            const int h = 2 * k + s_;
            float u = 0.f;
            #pragma unroll
            for (int i = 0; i < QDIM; ++i)
                u = fmaf(W1[i * HDIM + h], W3[j * QDIM + i], u);
            const float w2 = W2[h * HDIM + j];
            float rs = 0.f;
            for (int jj = 0; jj < HDIM; ++jj) rs += W2[h * HDIM + jj];
            w2p[s_] = w2; up[s_] = u; mp[s_] = u * (w2 - INV_H * rs);
        }
        wsu[WS_W2TH + j * 28 + k] = h2bits(w2p[0], w2p[1]);
        wsu[WS_UTH  + j * 28 + k] = h2bits(up[0], up[1]);
        wsu[WS_MH   + j * 28 + k] = h2bits(mp[0], mp[1]);
    }
    for (int idx = tid; idx < HDIM * 16; idx += 256) {
        const int j = idx / 16, k = idx % 16;
        wsu[WS_W3H + j * 16 + k] = h2bits(W3[j * QDIM + 2 * k], W3[j * QDIM + 2 * k + 1]);
    }
    if (tid < HDIM) {
        float acc = 0.f;
        #pragma unroll
        for (int i = 0; i < QDIM; ++i) {
            float rs1 = 0.f;
            for (int h = 0; h < HDIM; ++h) rs1 += W1[i * HDIM + h];
            acc = fmaf(rs1, W3[tid * QDIM + i], acc);
        }
        ws[WS_JV + tid * 4 + 0] = g2[tid];
        ws[WS_JV + tid * 4 + 1] = be2[tid];
        ws[WS_JV + tid * 4 + 2] = b2[tid];
        ws[WS_JV + tid * 4 + 3] = acc;
        ws[WS_HV + tid * 4 + 0] = b1[tid];
        ws[WS_HV + tid * 4 + 1] = g1[tid];
        ws[WS_HV + tid * 4 + 2] = be1[tid];
        ws[WS_HV + tid * 4 + 3] = 0.f;
    }
}

// ---- forward dots (f32 accumulate via FDOT2) ----
#define DOT64(res, rowp, P)                                           \
    {                                                                 \
        float q0 = 0.f, q1 = 0.f, q2 = 0.f, q3 = 0.f;                 \
        const uint4* R_ = (const uint4*)(rowp);                       \
        _Pragma("unroll")                                             \
        for (int c_ = 0; c_ < 8; ++c_) {                              \
            const uint4 u_ = R_[c_];                                  \
            q0 = FDOT2(as_h2(u_.x), (P)[4*c_ + 0], q0);               \
            q1 = FDOT2(as_h2(u_.y), (P)[4*c_ + 1], q1);               \
            q2 = FDOT2(as_h2(u_.z), (P)[4*c_ + 2], q2);               \
            q3 = FDOT2(as_h2(u_.w), (P)[4*c_ + 3], q3);               \
        }                                                             \
        res = (q0 + q1) + (q2 + q3);                                  \
    }
#define DOT56(res, rowp, P)                                           \
    {                                                                 \
        float q0 = 0.f, q1 = 0.f, q2 = 0.f, q3 = 0.f;                 \
        const uint4* R_ = (const uint4*)(rowp);                       \
        _Pragma("unroll")                                             \
        for (int c_ = 0; c_ < 7; ++c_) {                              \
            const uint4 u_ = R_[c_];                                  \
            q0 = FDOT2(as_h2(u_.x), (P)[4*c_ + 0], q0);               \
            q1 = FDOT2(as_h2(u_.y), (P)[4*c_ + 1], q1);               \
            q2 = FDOT2(as_h2(u_.z), (P)[4*c_ + 2], q2);               \
            q3 = FDOT2(as_h2(u_.w), (P)[4*c_ + 3], q3);               \
        }                                                             \
        res = (q0 + q1) + (q2 + q3);                                  \
    }

// ---- trace dots: pure packed-f16 (v_pk_fma_f16) ----
#define LDROW7(RB, SRC) { const uint4* S_ = (const uint4*)(SRC);      \
    _Pragma("unroll") for (int c_ = 0; c_ < 7; ++c_) RB[c_] = S_[c_]; }
#define LDROW4(RB, SRC) { const uint4* S_ = (const uint4*)(SRC);      \
    _Pragma("unroll") for (int c_ = 0; c_ < 4; ++c_) RB[c_] = S_[c_]; }

#define PKDOT_RB(res, RB, P)                                          \
    {                                                                 \
        h2f a0 = mk_h2(0.f, 0.f), a1_ = a0;                           \
        _Pragma("unroll")                                             \
        for (int c_ = 0; c_ < 7; ++c_) {                              \
            a0  = as_h2(RB[c_].x) * (P)[4*c_ + 0] + a0;               \
            a1_ = as_h2(RB[c_].y) * (P)[4*c_ + 1] + a1_;              \
            a0  = as_h2(RB[c_].z) * (P)[4*c_ + 2] + a0;               \
            a1_ = as_h2(RB[c_].w) * (P)[4*c_ + 3] + a1_;              \
        }                                                             \
        a0 = a0 + a1_;                                                \
        res = (float)a0[0] + (float)a0[1];                            \
    }

#define PK3DOT_RB(rA, rB, rC, RB, PA, PB, PC)                         \
    {                                                                 \
        h2f aA = mk_h2(0.f, 0.f), aB = aA, aC = aA;                   \
        _Pragma("unroll")                                             \
        for (int c_ = 0; c_ < 7; ++c_) {                              \
            const h2f x_ = as_h2(RB[c_].x), y_ = as_h2(RB[c_].y);     \
            const h2f z_ = as_h2(RB[c_].z), w_ = as_h2(RB[c_].w);     \
            aA = x_ * (PA)[4*c_ + 0] + aA;                            \
            aB = x_ * (PB)[4*c_ + 0] + aB;                            \
            aC = x_ * (PC)[4*c_ + 0] + aC;                            \
            aA = y_ * (PA)[4*c_ + 1] + aA;                            \
            aB = y_ * (PB)[4*c_ + 1] + aB;                            \
            aC = y_ * (PC)[4*c_ + 1] + aC;                            \
            aA = z_ * (PA)[4*c_ + 2] + aA;                            \
            aB = z_ * (PB)[4*c_ + 2] + aB;                            \
            aC = z_ * (PC)[4*c_ + 2] + aC;                            \
            aA = w_ * (PA)[4*c_ + 3] + aA;                            \
            aB = w_ * (PB)[4*c_ + 3] + aB;                            \
            aC = w_ * (PC)[4*c_ + 3] + aC;                            \
        }                                                             \
        rA = (float)aA[0] + (float)aA[1];                             \
        rB = (float)aB[0] + (float)aB[1];                             \
        rC = (float)aC[0] + (float)aC[1];                             \
    }

#define SAXPY_RB7(RB, sh, D)                                          \
    {                                                                 \
        _Pragma("unroll")                                             \
        for (int c_ = 0; c_ < 7; ++c_) {                              \
            (D)[4*c_ + 0] = as_h2(RB[c_].x) * (sh) + (D)[4*c_ + 0];   \
            (D)[4*c_ + 1] = as_h2(RB[c_].y) * (sh) + (D)[4*c_ + 1];   \
            (D)[4*c_ + 2] = as_h2(RB[c_].z) * (sh) + (D)[4*c_ + 2];   \
            (D)[4*c_ + 3] = as_h2(RB[c_].w) * (sh) + (D)[4*c_ + 3];   \
        }                                                             \
    }
#define SAXPY_RB4(RB, sh, D)                                          \
    {                                                                 \
        _Pragma("unroll")                                             \
        for (int c_ = 0; c_ < 4; ++c_) {                              \
            (D)[4*c_ + 0] = as_h2(RB[c_].x) * (sh) + (D)[4*c_ + 0];   \
            (D)[4*c_ + 1] = as_h2(RB[c_].y) * (sh) + (D)[4*c_ + 1];   \
            (D)[4*c_ + 2] = as_h2(RB[c_].z) * (sh) + (D)[4*c_ + 2];   \
            (D)[4*c_ + 3] = as_h2(RB[c_].w) * (sh) + (D)[4*c_ + 3];   \
        }                                                             \
    }

__global__ __launch_bounds__(256, 2)
void ode2vae_main(const float* __restrict__ z0, const float* __restrict__ logp0,
                  const float* __restrict__ b3,
                  const float* __restrict__ wsc,  // const + uniform idx -> s_load
                  float* out)                     // we read our own writes
{
    __shared__ float lds[LDS_FLOATS];
    const int tid = threadIdx.x;
    const int n = blockIdx.x * 256 + tid;

    // stage only the LDS-resident tables (W1TH, W2TH, UTH)
    {
        const u32* src = (const u32*)wsc;
        u32* dst = (u32*)(lds + SLOT_FLOATS);
        for (int i = tid; i < 1600; i += 256) dst[LT_W1TH + i] = src[WS_W1TH + i];
        for (int i = tid; i < 1400; i += 256) dst[LT_W2TH + i] = src[WS_W2TH + i];
        for (int i = tid; i < 1400; i += 256) dst[LT_UTH + i]  = src[WS_UTH + i];
    }
    __syncthreads();

    float* const L = lds + tid;                         // slot k at L[k*256]
    const u32* LW1TH = (const u32*)(lds + SLOT_FLOATS) + LT_W1TH;
    const u32* LW2TH = (const u32*)(lds + SLOT_FLOATS) + LT_W2TH;
    const u32* LUTH  = (const u32*)(lds + SLOT_FLOATS) + LT_UTH;
    // scalar-pipe tables (global, uniform address -> s_load, K$-cached)
    const u32* GMH   = (const u32*)wsc + WS_MH;
    const u32* GW3H  = (const u32*)wsc + WS_W3H;
    const f4a* GJV   = (const f4a*)(wsc + WS_JV);
    const f4a* GHV   = (const f4a*)(wsc + WS_HV);

    float zq[QDIM];
    {
        const f4a* zp = (const f4a*)(z0 + (size_t)n * DDIM);
        #pragma unroll
        for (int k = 0; k < 8; ++k) {
            f4a v = zp[k];
            zq[4*k] = v[0]; zq[4*k+1] = v[1]; zq[4*k+2] = v[2]; zq[4*k+3] = v[3];
        }
    }
    float lp = logp0[n];

    for (int s = 0; s < STEPS; ++s) {
        float* const odst = out + ((size_t)s * NPART + (size_t)n) * ODIM;
        const float* const zsprev = (s == 0)
            ? (z0 + (size_t)n * DDIM + QDIM)
            : (out + ((size_t)(s - 1) * NPART + (size_t)n) * ODIM + QDIM);

        // ======== A: load zs; pack z; a1 rows -> slots (f32) ========
        float zs[QDIM];
        #pragma unroll
        for (int k = 0; k < 8; ++k) {
            f4u v = *(const f4u*)(zsprev + 4 * k);
            zs[4*k] = v[0]; zs[4*k+1] = v[1]; zs[4*k+2] = v[2]; zs[4*k+3] = v[3];
        }
        h2f zp[32];
        #pragma unroll
        for (int k = 0; k < 16; ++k) zp[k] = mk_h2(zq[2*k], zq[2*k+1]);
        #pragma unroll
        for (int k = 0; k < 16; ++k) zp[16 + k] = mk_h2(zs[2*k], zs[2*k+1]);

        float m1a = 0.f, v1a = 0.f;
        #pragma unroll 1
        for (int h = 0; h < HDIM; ++h) {
            float a1h;
            DOT64(a1h, LW1TH + h * 32, zp);
            const f4a hv = GHV[h];
            a1h += hv[0];
            L[h * 256] = a1h;
            m1a += a1h;
            v1a = fmaf(a1h, a1h, v1a);
        }
        #pragma unroll
        for (int k = 0; k < QDIM; ++k) zs[k] = fmaf(DT, zq[k], zs[k]);
        #pragma unroll
        for (int k = 0; k < 8; ++k) {
            f4u v = {zs[4*k], zs[4*k+1], zs[4*k+2], zs[4*k+3]};
            *(f4u*)(odst + QDIM + 4 * k) = v;
        }
        const float m1 = m1a * INV_H;
        float var1 = v1a * INV_H - m1 * m1;
        var1 = var1 > 0.f ? var1 : 0.f;
        const float r1 = rsqrtf(var1 + LN_EPS);

        // ======== B+G: xh1p, hhp, w1vp, w1xp (one exp per half) ========
        h2f xh1p[28], hhp[28], w1vp[28], w1xp[28];
        #pragma unroll
        for (int hp = 0; hp < 25; ++hp) {
            const float xa = (L[(2*hp) * 256] - m1) * r1;
            const float xb = (L[(2*hp + 1) * 256] - m1) * r1;
            const f4a hva = GHV[2*hp], hvb = GHV[2*hp + 1];
            const float ya = fmaf(xa, hva[1], hva[2]);
            const float yb = fmaf(xb, hvb[1], hvb[2]);
            const float ea = __expf(ya), eb = __expf(yb);
            const float ca = (ya > 0.f) ? ya : (ea - 1.f);
            const float cb = (yb > 0.f) ? yb : (eb - 1.f);
            const float wa = ((ya > 0.f) ? 1.f : ea) * (hva[1] * r1);
            const float wb = ((yb > 0.f) ? 1.f : eb) * (hvb[1] * r1);
            xh1p[hp] = mk_h2(xa, xb);
            hhp[hp]  = mk_h2(ca, cb);
            w1vp[hp] = mk_h2(wa, wb);
            w1xp[hp] = mk_h2(wa * xa, wb * xb);
        }
        #pragma unroll
        for (int hp = 25; hp < 28; ++hp) {
            xh1p[hp] = mk_h2(0.f, 0.f); hhp[hp] = mk_h2(0.f, 0.f);
            w1vp[hp] = mk_h2(0.f, 0.f); w1xp[hp] = mk_h2(0.f, 0.f);
        }

        // ======== C: a2 -> slots (f32 acc) ========
        float m2a = 0.f, v2a = 0.f;
        #pragma unroll 1
        for (int j = 0; j < HDIM; ++j) {
            float a2j;
            DOT56(a2j, LW2TH + j * 28, hhp);
            const f4a jv = GJV[j];
            a2j += jv[2];
            L[j * 256] = a2j;
            m2a += a2j;
            v2a = fmaf(a2j, a2j, v2a);
        }
        const float m2 = m2a * INV_H;
        float var2 = v2a * INV_H - m2 * m2;
        var2 = var2 > 0.f ? var2 : 0.f;
        const float r2 = rsqrtf(var2 + LN_EPS);

        // ======== P1 (D1+F2): per j: UT row once -> t-dot + duy saxpy ========
        h2f duyp[28];
        #pragma unroll
        for (int k = 0; k < 28; ++k) duyp[k] = mk_h2(0.f, 0.f);
        float suA = 0.f, syA = 0.f, tuA = 0.f, tyA = 0.f;
        #pragma unroll 1
        for (int j = 0; j < HDIM; ++j) {
            uint4 RB[7];
            LDROW7(RB, LUTH + j * 28);
            const float x2 = (L[j * 256] - m2) * r2;
            const f4a jv = GJV[j];
            const float y = fmaf(x2, jv[0], jv[1]);
            const float e = __expf(y);
            const float w2vj = ((y > 0.f) ? 1.f : e) * (jv[0] * r2);
            float t;
            PKDOT_RB(t, RB, xh1p);
            const float tw = w2vj * t;
            const float y3 = x2 * w2vj;
            const h2f y3h = mk_h2(y3, y3);
            SAXPY_RB7(RB, y3h, duyp);
            L[j * 256] = pack2h(x2, tw);
            tuA += tw; tyA = fmaf(tw, x2, tyA);
            const float sw = jv[3] * w2vj;
            suA += sw; syA = fmaf(sw, x2, syA);
        }
        const float suH = suA * INV_H, syH = syA * INV_H;
        const float tuH = tuA * INV_H, tyH = tyA * INV_H;

        // wduy = duyp * w1vp
        #pragma unroll
        for (int k = 0; k < 28; ++k) duyp[k] = duyp[k] * w1vp[k];

        // ======== P2 (F1+T1A+T1c+dv): one j-pass ========
        float S2 = 0.f, S3 = 0.f, T1c = 0.f, T1A = 0.f;
        h2f dvp[16];
        #pragma unroll
        for (int k = 0; k < 16; ++k) dvp[k] = mk_h2(0.f, 0.f);
        #pragma unroll 1
        for (int j = 0; j < HDIM; ++j) {
            // scalar-pipe rows issued early (M + W3H via s_load)
            uint4 RC[7];
            LDROW7(RC, GMH + j * 28);
            uint4 RB4[4];
            LDROW4(RB4, GW3H + j * 16);
            float x2, tw; unpack2h(L[j * 256], x2, tw);
            const f4a jv = GJV[j];
            const float y = fmaf(x2, jv[0], jv[1]);
            const float e = __expf(y);
            const float w2vj = ((y > 0.f) ? 1.f : e) * (jv[0] * r2);
            const float h2v = (y > 0.f) ? y : (e - 1.f);
            const float q1 = fmaf(-syH, x2, jv[3] * w2vj - suH);
            const float q2 = fmaf(-tyH, x2, tw - tuH);
            uint4 RB[7];
            LDROW7(RB, LW2TH + j * 28);
            float cS2, cS3, cTc;
            PK3DOT_RB(cS2, cS3, cTc, RB, w1vp, w1xp, duyp);
            float cTA;
            PKDOT_RB(cTA, RC, w1vp);
            const h2f hb = mk_h2(h2v, h2v);
            SAXPY_RB4(RB4, hb, dvp);
            S2  = fmaf(q1, cS2, S2);
            S3  = fmaf(q2, cS3, S3);
            T1c = fmaf(x2, cTc, T1c);
            T1A = fmaf(w2vj, cTA, T1A);
        }
        const float tr = T1A - (T1c + S2 + S3) * INV_H;

        // ======== update zq, lp; store ========
        lp = fmaf(-DT, tr, lp);
        #pragma unroll
        for (int k = 0; k < 16; ++k) {
            const float da = (float)dvp[k][0] + b3[2*k];
            const float db = (float)dvp[k][1] + b3[2*k + 1];
            zq[2*k]     = fmaf(DT, da, zq[2*k]);
            zq[2*k + 1] = fmaf(DT, db, zq[2*k + 1]);
        }
        #pragma unroll
        for (int k = 0; k < 8; ++k) {
            f4u v = {zq[4*k], zq[4*k+1], zq[4*k+2], zq[4*k+3]};
            *(f4u*)(odst + 4 * k) = v;
        }
        odst[DDIM] = lp;
    }
}

extern "C" void kernel_launch(void* const* d_in, const int* in_sizes, int n_in,
                              void* d_out, int out_size, void* d_ws, size_t ws_size,
                              hipStream_t stream)
{
    const float* z0    = (const float*)d_in[0];
    const float* logp0 = (const float*)d_in[1];
    const float* W1    = (const float*)d_in[2];
    const float* b1    = (const float*)d_in[3];
    const float* g1    = (const float*)d_in[4];
    const float* be1   = (const float*)d_in[5];
    const float* W2    = (const float*)d_in[6];
    const float* b2    = (const float*)d_in[7];
    const float* g2    = (const float*)d_in[8];
    const float* be2   = (const float*)d_in[9];
    const float* W3    = (const float*)d_in[10];
    const float* b3    = (const float*)d_in[11];
    float* out = (float*)d_out;
    float* ws  = (float*)d_ws;

    hipLaunchKernelGGL(ode2vae_setup, dim3(1), dim3(256), 0, stream,
                       W1, W2, W3, b1, g1, be1, b2, g2, be2, ws);
    hipLaunchKernelGGL(ode2vae_main, dim3(NPART / 256), dim3(256), 0, stream,
                       z0, logp0, b3, ws, out);
}

// Round 12
// 1346.588 us; speedup vs baseline: 3.7930x; 1.0225x over previous
//
#include <hip/hip_runtime.h>
#include <hip/hip_fp16.h>

#define NPART 131072
#define QDIM 32
#define DDIM 64
#define HDIM 50
#define STEPS 16
#define DT 0.1f
#define LN_EPS 1e-5f
#define INV_H 0.02f   // 1/50
#define ODIM 65       // output row stride

// ---- ws weight tables (u32 units; f16 pairs over the contracted dim) ----
#define WS_W1TH 0      // [50][32]  pairs over d (64)
#define WS_W2TH 1600   // [50][28]  pairs over h (50, pad 56)
#define WS_UTH  3000   // [50][28]
#define WS_MH   4400   // [50][28]
#define WS_W3H  5800   // [50][16]  pairs over i (32)
#define WS_JV   6600   // f32 [50][4] {g2, be2, b2, sv}
#define WS_HV   6800   // f32 [50][4] {b1, g1, be1, 0}
#define WS_TOT  7000   // 28000 B

// LDS-resident tables: W2TH + UTH only (2800 u32 = 11.2 KB)
#define LT_W2TH 0
#define LT_UTH  1400
#define LT_TOT  2800

#define SLOT_FLOATS (HDIM * 256)              // 12800 floats = 51.2 KB
#define LDS_FLOATS  (SLOT_FLOATS + LT_TOT)    // 15600 floats = 62.4 KB

typedef float f4a __attribute__((ext_vector_type(4)));
typedef float f4u __attribute__((ext_vector_type(4), aligned(4)));
typedef unsigned int u32;
typedef _Float16 h2f __attribute__((ext_vector_type(2)));

__device__ __forceinline__ h2f as_h2(u32 x) { h2f r; __builtin_memcpy(&r, &x, 4); return r; }
__device__ __forceinline__ u32 h2bits(float a, float b) {
    h2f p; p[0] = (_Float16)a; p[1] = (_Float16)b;
    u32 r; __builtin_memcpy(&r, &p, 4); return r;
}
__device__ __forceinline__ h2f mk_h2(float a, float b) {
    h2f p; p[0] = (_Float16)a; p[1] = (_Float16)b; return p;
}

#if __has_builtin(__builtin_amdgcn_fdot2)
#define FDOT2(a, b, c) __builtin_amdgcn_fdot2((a), (b), (c), false)
#else
#define FDOT2(a, b, c) ((float)(a)[0] * (float)(b)[0] + ((float)(a)[1] * (float)(b)[1] + (c)))
#endif

// ---------------- setup (same table contents as R9-R11) ----------------
__global__ void ode2vae_setup(const float* __restrict__ W1,
                              const float* __restrict__ W2,
                              const float* __restrict__ W3,
                              const float* __restrict__ b1, const float* __restrict__ g1,
                              const float* __restrict__ be1,
                              const float* __restrict__ b2, const float* __restrict__ g2,
                              const float* __restrict__ be2,
                              float* __restrict__ ws)
{
    const int tid = threadIdx.x;
    u32* wsu = (u32*)ws;
    for (int i = tid; i < WS_TOT; i += 256) wsu[i] = 0u;
    __syncthreads();
    for (int idx = tid; idx < HDIM * 32; idx += 256) {
        const int h = idx / 32, k = idx % 32;
        wsu[WS_W1TH + h * 32 + k] = h2bits(W1[(2 * k) * HDIM + h], W1[(2 * k + 1) * HDIM + h]);
    }
    for (int idx = tid; idx < HDIM * 25; idx += 256) {
        const int j = idx / 25, k = idx % 25;
        float w2p[2], up[2], mp[2];
        #pragma unroll
        for (int s_ = 0; s_ < 2; ++s_) {
            const int h = 2 * k + s_;
            float u = 0.f;
            #pragma unroll
            for (int i = 0; i < QDIM; ++i)
                u = fmaf(W1[i * HDIM + h], W3[j * QDIM + i], u);
            const float w2 = W2[h * HDIM + j];
            float rs = 0.f;
            for (int jj = 0; jj < HDIM; ++jj) rs += W2[h * HDIM + jj];
            w2p[s_] = w2; up[s_] = u; mp[s_] = u * (w2 - INV_H * rs);
        }
        wsu[WS_W2TH + j * 28 + k] = h2bits(w2p[0], w2p[1]);
        wsu[WS_UTH  + j * 28 + k] = h2bits(up[0], up[1]);
        wsu[WS_MH   + j * 28 + k] = h2bits(mp[0], mp[1]);
    }
    for (int idx = tid; idx < HDIM * 16; idx += 256) {
        const int j = idx / 16, k = idx % 16;
        wsu[WS_W3H + j * 16 + k] = h2bits(W3[j * QDIM + 2 * k], W3[j * QDIM + 2 * k + 1]);
    }
    if (tid < HDIM) {
        float acc = 0.f;
        #pragma unroll
        for (int i = 0; i < QDIM; ++i) {
            float rs1 = 0.f;
            for (int h = 0; h < HDIM; ++h) rs1 += W1[i * HDIM + h];
            acc = fmaf(rs1, W3[tid * QDIM + i], acc);
        }
        ws[WS_JV + tid * 4 + 0] = g2[tid];
        ws[WS_JV + tid * 4 + 1] = be2[tid];
        ws[WS_JV + tid * 4 + 2] = b2[tid];
        ws[WS_JV + tid * 4 + 3] = acc;
        ws[WS_HV + tid * 4 + 0] = b1[tid];
        ws[WS_HV + tid * 4 + 1] = g1[tid];
        ws[WS_HV + tid * 4 + 2] = be1[tid];
        ws[WS_HV + tid * 4 + 3] = 0.f;
    }
}

// ---- forward dots (f32 accumulate) ----
#define DOT64(res, rowp, P)                                           \
    {                                                                 \
        float q0 = 0.f, q1 = 0.f, q2 = 0.f, q3 = 0.f;                 \
        const uint4* R_ = (const uint4*)(rowp);                       \
        _Pragma("unroll")                                             \
        for (int c_ = 0; c_ < 8; ++c_) {                              \
            const uint4 u_ = R_[c_];                                  \
            q0 = FDOT2(as_h2(u_.x), (P)[4*c_ + 0], q0);               \
            q1 = FDOT2(as_h2(u_.y), (P)[4*c_ + 1], q1);               \
            q2 = FDOT2(as_h2(u_.z), (P)[4*c_ + 2], q2);               \
            q3 = FDOT2(as_h2(u_.w), (P)[4*c_ + 3], q3);               \
        }                                                             \
        res = (q0 + q1) + (q2 + q3);                                  \
    }
#define DOT56(res, rowp, P)                                           \
    {                                                                 \
        float q0 = 0.f, q1 = 0.f, q2 = 0.f, q3 = 0.f;                 \
        const uint4* R_ = (const uint4*)(rowp);                       \
        _Pragma("unroll")                                             \
        for (int c_ = 0; c_ < 7; ++c_) {                              \
            const uint4 u_ = R_[c_];                                  \
            q0 = FDOT2(as_h2(u_.x), (P)[4*c_ + 0], q0);               \
            q1 = FDOT2(as_h2(u_.y), (P)[4*c_ + 1], q1);               \
            q2 = FDOT2(as_h2(u_.z), (P)[4*c_ + 2], q2);               \
            q3 = FDOT2(as_h2(u_.w), (P)[4*c_ + 3], q3);               \
        }                                                             \
        res = (q0 + q1) + (q2 + q3);                                  \
    }

// ---- row loads ----
#define LDROW7(RB, SRC) { const uint4* S_ = (const uint4*)(SRC);      \
    _Pragma("unroll") for (int c_ = 0; c_ < 7; ++c_) RB[c_] = S_[c_]; }
#define LDROW4(RB, SRC) { const uint4* S_ = (const uint4*)(SRC);      \
    _Pragma("unroll") for (int c_ = 0; c_ < 4; ++c_) RB[c_] = S_[c_]; }

// ---- pk-f16 dot of preloaded row ----
#define PKDOT_RB(res, RB, P)                                          \
    {                                                                 \
        h2f a0 = mk_h2(0.f, 0.f), a1_ = a0;                           \
        _Pragma("unroll")                                             \
        for (int c_ = 0; c_ < 7; ++c_) {                              \
            a0  = as_h2(RB[c_].x) * (P)[4*c_ + 0] + a0;               \
            a1_ = as_h2(RB[c_].y) * (P)[4*c_ + 1] + a1_;              \
            a0  = as_h2(RB[c_].z) * (P)[4*c_ + 2] + a0;               \
            a1_ = as_h2(RB[c_].w) * (P)[4*c_ + 3] + a1_;              \
        }                                                             \
        a0 = a0 + a1_;                                                \
        res = (float)a0[0] + (float)a0[1];                            \
    }

// ---- dot + saxpy sharing one row (UT: t-dot with PA, duy += row*ys) ----
#define PKDOT_SAX_RB(res, RB, PA, ys, D)                              \
    {                                                                 \
        h2f a0 = mk_h2(0.f, 0.f), a1_ = a0;                           \
        _Pragma("unroll")                                             \
        for (int c_ = 0; c_ < 7; ++c_) {                              \
            const h2f x_ = as_h2(RB[c_].x), y_ = as_h2(RB[c_].y);     \
            const h2f z_ = as_h2(RB[c_].z), w_ = as_h2(RB[c_].w);     \
            a0  = x_ * (PA)[4*c_ + 0] + a0;                           \
            (D)[4*c_ + 0] = x_ * (ys) + (D)[4*c_ + 0];                \
            a1_ = y_ * (PA)[4*c_ + 1] + a1_;                          \
            (D)[4*c_ + 1] = y_ * (ys) + (D)[4*c_ + 1];                \
            a0  = z_ * (PA)[4*c_ + 2] + a0;                           \
            (D)[4*c_ + 2] = z_ * (ys) + (D)[4*c_ + 2];                \
            a1_ = w_ * (PA)[4*c_ + 3] + a1_;                          \
            (D)[4*c_ + 3] = w_ * (ys) + (D)[4*c_ + 3];                \
        }                                                             \
        a0 = a0 + a1_;                                                \
        res = (float)a0[0] + (float)a0[1];                            \
    }

// ---- 2 dots + saxpy sharing one row (W2T: cS2, cS3, php += row*x2) ----
#define PK2DOT_SAX_RB(rA, rB, RB, PA, PB, xs, D)                      \
    {                                                                 \
        h2f aA = mk_h2(0.f, 0.f), aB = aA;                            \
        _Pragma("unroll")                                             \
        for (int c_ = 0; c_ < 7; ++c_) {                              \
            const h2f x_ = as_h2(RB[c_].x), y_ = as_h2(RB[c_].y);     \
            const h2f z_ = as_h2(RB[c_].z), w_ = as_h2(RB[c_].w);     \
            aA = x_ * (PA)[4*c_ + 0] + aA;                            \
            aB = x_ * (PB)[4*c_ + 0] + aB;                            \
            (D)[4*c_ + 0] = x_ * (xs) + (D)[4*c_ + 0];                \
            aA = y_ * (PA)[4*c_ + 1] + aA;                            \
            aB = y_ * (PB)[4*c_ + 1] + aB;                            \
            (D)[4*c_ + 1] = y_ * (xs) + (D)[4*c_ + 1];                \
            aA = z_ * (PA)[4*c_ + 2] + aA;                            \
            aB = z_ * (PB)[4*c_ + 2] + aB;                            \
            (D)[4*c_ + 2] = z_ * (xs) + (D)[4*c_ + 2];                \
            aA = w_ * (PA)[4*c_ + 3] + aA;                            \
            aB = w_ * (PB)[4*c_ + 3] + aB;                            \
            (D)[4*c_ + 3] = w_ * (xs) + (D)[4*c_ + 3];                \
        }                                                             \
        rA = (float)aA[0] + (float)aA[1];                             \
        rB = (float)aB[0] + (float)aB[1];                             \
    }

#define SAXPY_RB4(RB, sh, D)                                          \
    {                                                                 \
        _Pragma("unroll")                                             \
        for (int c_ = 0; c_ < 4; ++c_) {                              \
            (D)[4*c_ + 0] = as_h2(RB[c_].x) * (sh) + (D)[4*c_ + 0];   \
            (D)[4*c_ + 1] = as_h2(RB[c_].y) * (sh) + (D)[4*c_ + 1];   \
            (D)[4*c_ + 2] = as_h2(RB[c_].z) * (sh) + (D)[4*c_ + 2];   \
            (D)[4*c_ + 3] = as_h2(RB[c_].w) * (sh) + (D)[4*c_ + 3];   \
        }                                                             \
    }

__global__ __launch_bounds__(256, 2)
void ode2vae_main(const float* __restrict__ z0, const float* __restrict__ logp0,
                  const float* __restrict__ b3,
                  const float* __restrict__ wsc,  // const + uniform idx -> s_load
                  float* out)                     // we read our own writes
{
    __shared__ float lds[LDS_FLOATS];
    const int tid = threadIdx.x;
    const int n = blockIdx.x * 256 + tid;

    // stage only W2TH + UTH into LDS
    {
        const u32* src = (const u32*)wsc;
        u32* dst = (u32*)(lds + SLOT_FLOATS);
        for (int i = tid; i < 1400; i += 256) dst[LT_W2TH + i] = src[WS_W2TH + i];
        for (int i = tid; i < 1400; i += 256) dst[LT_UTH + i]  = src[WS_UTH + i];
    }
    __syncthreads();

    float* const L = lds + tid;                         // slot k at L[k*256]
    const u32* LW2TH = (const u32*)(lds + SLOT_FLOATS) + LT_W2TH;
    const u32* LUTH  = (const u32*)(lds + SLOT_FLOATS) + LT_UTH;
    // scalar-pipe tables (global, uniform address -> s_load, K$-cached)
    const u32* GW1TH = (const u32*)wsc + WS_W1TH;
    const u32* GMH   = (const u32*)wsc + WS_MH;
    const u32* GW3H  = (const u32*)wsc + WS_W3H;
    const f4a* GJV   = (const f4a*)(wsc + WS_JV);
    const f4a* GHV   = (const f4a*)(wsc + WS_HV);

    float lp = logp0[n];
    const float* const zrow0 = z0 + (size_t)n * DDIM;

    for (int s = 0; s < STEPS; ++s) {
        float* const odst = out + ((size_t)s * NPART + (size_t)n) * ODIM;
        const float* const zprev = (s == 0) ? zrow0
            : (out + ((size_t)(s - 1) * NPART + (size_t)n) * ODIM);

        // ======== A: load z (both halves), pack; a1 rows via SCALAR W1T ========
        float zq[QDIM], zs[QDIM];
        #pragma unroll
        for (int k = 0; k < 8; ++k) {
            f4u v = *(const f4u*)(zprev + 4 * k);
            zq[4*k] = v[0]; zq[4*k+1] = v[1]; zq[4*k+2] = v[2]; zq[4*k+3] = v[3];
        }
        #pragma unroll
        for (int k = 0; k < 8; ++k) {
            f4u v = *(const f4u*)(zprev + QDIM + 4 * k);
            zs[4*k] = v[0]; zs[4*k+1] = v[1]; zs[4*k+2] = v[2]; zs[4*k+3] = v[3];
        }
        h2f zp[32];
        #pragma unroll
        for (int k = 0; k < 16; ++k) zp[k] = mk_h2(zq[2*k], zq[2*k+1]);
        #pragma unroll
        for (int k = 0; k < 16; ++k) zp[16 + k] = mk_h2(zs[2*k], zs[2*k+1]);

        float m1a = 0.f, v1a = 0.f;
        #pragma unroll 1
        for (int h = 0; h < HDIM; ++h) {
            float a1h;
            DOT64(a1h, GW1TH + h * 32, zp);
            const f4a hv = GHV[h];
            a1h += hv[0];
            L[h * 256] = a1h;
            m1a += a1h;
            v1a = fmaf(a1h, a1h, v1a);
        }
        // zs_new = zs + DT*zq (old zq); store; zq/zs regs die after this
        #pragma unroll
        for (int k = 0; k < QDIM; ++k) zs[k] = fmaf(DT, zq[k], zs[k]);
        #pragma unroll
        for (int k = 0; k < 8; ++k) {
            f4u v = {zs[4*k], zs[4*k+1], zs[4*k+2], zs[4*k+3]};
            *(f4u*)(odst + QDIM + 4 * k) = v;
        }
        const float m1 = m1a * INV_H;
        float var1 = v1a * INV_H - m1 * m1;
        var1 = var1 > 0.f ? var1 : 0.f;
        const float r1 = rsqrtf(var1 + LN_EPS);

        // ======== B+G: xh1p, hhp, w1vp, w1xp ========
        h2f xh1p[28], hhp[28], w1vp[28], w1xp[28];
        #pragma unroll
        for (int hp = 0; hp < 25; ++hp) {
            const float xa = (L[(2*hp) * 256] - m1) * r1;
            const float xb = (L[(2*hp + 1) * 256] - m1) * r1;
            const f4a hva = GHV[2*hp], hvb = GHV[2*hp + 1];
            const float ya = fmaf(xa, hva[1], hva[2]);
            const float yb = fmaf(xb, hvb[1], hvb[2]);
            const float ea = __expf(ya), eb = __expf(yb);
            const float ca = (ya > 0.f) ? ya : (ea - 1.f);
            const float cb = (yb > 0.f) ? yb : (eb - 1.f);
            const float wa = ((ya > 0.f) ? 1.f : ea) * (hva[1] * r1);
            const float wb = ((yb > 0.f) ? 1.f : eb) * (hvb[1] * r1);
            xh1p[hp] = mk_h2(xa, xb);
            hhp[hp]  = mk_h2(ca, cb);
            w1vp[hp] = mk_h2(wa, wb);
            w1xp[hp] = mk_h2(wa * xa, wb * xb);
        }
        #pragma unroll
        for (int hp = 25; hp < 28; ++hp) {
            xh1p[hp] = mk_h2(0.f, 0.f); hhp[hp] = mk_h2(0.f, 0.f);
            w1vp[hp] = mk_h2(0.f, 0.f); w1xp[hp] = mk_h2(0.f, 0.f);
        }

        // ======== C: a2 -> slots (f32 acc, LDS W2T rows) ========
        float m2a = 0.f, v2a = 0.f;
        #pragma unroll 1
        for (int j = 0; j < HDIM; ++j) {
            float a2j;
            DOT56(a2j, LW2TH + j * 28, hhp);
            const f4a jv = GJV[j];
            a2j += jv[2];
            L[j * 256] = a2j;
            m2a += a2j;
            v2a = fmaf(a2j, a2j, v2a);
        }
        const float m2 = m2a * INV_H;
        float var2 = v2a * INV_H - m2 * m2;
        var2 = var2 > 0.f ? var2 : 0.f;
        const float r2 = rsqrtf(var2 + LN_EPS);

        // ======== FUSED j-pass: every weight row read ONCE ========
        h2f duyp[28], php[28];
        #pragma unroll
        for (int k = 0; k < 28; ++k) { duyp[k] = mk_h2(0.f, 0.f); php[k] = mk_h2(0.f, 0.f); }
        h2f dvp[16];
        #pragma unroll
        for (int k = 0; k < 16; ++k) dvp[k] = mk_h2(0.f, 0.f);
        float suA = 0.f, syA = 0.f, tuA = 0.f, tyA = 0.f;
        float A2a = 0.f, A2b = 0.f, A2c = 0.f;
        float A3a = 0.f, A3b = 0.f, A3c = 0.f;
        float T1A = 0.f;
        #pragma unroll 1
        for (int j = 0; j < HDIM; ++j) {
            const float x2 = (L[j * 256] - m2) * r2;
            const f4a jv = GJV[j];
            const float y = fmaf(x2, jv[0], jv[1]);
            const float e = __expf(y);
            const float w2vj = ((y > 0.f) ? 1.f : e) * (jv[0] * r2);
            const float h2v = (y > 0.f) ? y : (e - 1.f);

            // UT row: t-dot (xh1p) + duy saxpy (y3)
            uint4 RU[7];
            LDROW7(RU, LUTH + j * 28);
            const float y3 = x2 * w2vj;
            const h2f y3h = mk_h2(y3, y3);
            float t;
            PKDOT_SAX_RB(t, RU, xh1p, y3h, duyp);

            // W2T row: cS2 (w1v), cS3 (w1x), php saxpy (x2)
            uint4 RW[7];
            LDROW7(RW, LW2TH + j * 28);
            const h2f x2h = mk_h2(x2, x2);
            float cS2, cS3;
            PK2DOT_SAX_RB(cS2, cS3, RW, w1vp, w1xp, x2h, php);

            // M row (scalar): cTA dot (w1v)
            uint4 RM[7];
            LDROW7(RM, GMH + j * 28);
            float cTA;
            PKDOT_RB(cTA, RM, w1vp);

            // W3 row (scalar): dv saxpy (h2)
            uint4 R3[4];
            LDROW4(R3, GW3H + j * 16);
            const h2f hb = mk_h2(h2v, h2v);
            SAXPY_RB4(R3, hb, dvp);

            // scalar accumulators
            const float svw = jv[3] * w2vj;
            const float tw  = w2vj * t;
            suA += svw; syA = fmaf(svw, x2, syA);
            tuA += tw;  tyA = fmaf(tw, x2, tyA);
            A2a = fmaf(svw, cS2, A2a); A2b += cS2; A2c = fmaf(x2, cS2, A2c);
            A3a = fmaf(tw,  cS3, A3a); A3b += cS3; A3c = fmaf(x2, cS3, A3c);
            T1A = fmaf(w2vj, cTA, T1A);
        }

        // ======== epilogue: reload zq early; assemble trace; update; store ====
        float zq2[QDIM];
        #pragma unroll
        for (int k = 0; k < 8; ++k) {
            f4u v = *(const f4u*)(zprev + 4 * k);
            zq2[4*k] = v[0]; zq2[4*k+1] = v[1]; zq2[4*k+2] = v[2]; zq2[4*k+3] = v[3];
        }

        const float suH = suA * INV_H, syH = syA * INV_H;
        const float tuH = tuA * INV_H, tyH = tyA * INV_H;
        const float S2 = A2a - suH * A2b - syH * A2c;
        const float S3 = A3a - tuH * A3b - tyH * A3c;
        // T1c = sum_h w1v*duy*ph
        float T1c;
        {
            h2f acc0 = mk_h2(0.f, 0.f), acc1 = acc0;
            #pragma unroll
            for (int k = 0; k < 28; k += 2) {
                acc0 = (w1vp[k] * duyp[k]) * php[k] + acc0;
                acc1 = (w1vp[k+1] * duyp[k+1]) * php[k+1] + acc1;
            }
            acc0 = acc0 + acc1;
            T1c = (float)acc0[0] + (float)acc0[1];
        }
        const float tr = T1A - (T1c + S2 + S3) * INV_H;

        lp = fmaf(-DT, tr, lp);
        #pragma unroll
        for (int k = 0; k < 16; ++k) {
            const float da = (float)dvp[k][0] + b3[2*k];
            const float db = (float)dvp[k][1] + b3[2*k + 1];
            zq2[2*k]     = fmaf(DT, da, zq2[2*k]);
            zq2[2*k + 1] = fmaf(DT, db, zq2[2*k + 1]);
        }
        #pragma unroll
        for (int k = 0; k < 8; ++k) {
            f4u v = {zq2[4*k], zq2[4*k+1], zq2[4*k+2], zq2[4*k+3]};
            *(f4u*)(odst + 4 * k) = v;
        }
        odst[DDIM] = lp;
    }
}

extern "C" void kernel_launch(void* const* d_in, const int* in_sizes, int n_in,
                              void* d_out, int out_size, void* d_ws, size_t ws_size,
                              hipStream_t stream)
{
    const float* z0    = (const float*)d_in[0];
    const float* logp0 = (const float*)d_in[1];
    const float* W1    = (const float*)d_in[2];
    const float* b1    = (const float*)d_in[3];
    const float* g1    = (const float*)d_in[4];
    const float* be1   = (const float*)d_in[5];
    const float* W2    = (const float*)d_in[6];
    const float* b2    = (const float*)d_in[7];
    const float* g2    = (const float*)d_in[8];
    const float* be2   = (const float*)d_in[9];
    const float* W3    = (const float*)d_in[10];
    const float* b3    = (const float*)d_in[11];
    float* out = (float*)d_out;
    float* ws  = (float*)d_ws;

    hipLaunchKernelGGL(ode2vae_setup, dim3(1), dim3(256), 0, stream,
                       W1, W2, W3, b1, g1, be1, b2, g2, be2, ws);
    hipLaunchKernelGGL(ode2vae_main, dim3(NPART / 256), dim3(256), 0, stream,
                       z0, logp0, b3, ws, out);
}